// Round 1
// baseline (3362.682 us; speedup 1.0000x reference)
//
#include <hip/hip_runtime.h>
#include <math.h>

constexpr int N = 50000;
constexpr int E = 800000;
constexpr int H = 64;

// ---- workspace layout (element offsets) ----
// per-graph float block
constexpr size_t X_OFF    = 0;                          // N*H   current node features
constexpr size_t HB_OFF   = X_OFF + (size_t)N*H;        // (N+1)*H  matmul output (row N = supernode)
constexpr size_t NO_OFF   = HB_OFF + (size_t)(N+1)*H;   // N   deg_out^-1/2
constexpr size_t NI_OFF   = NO_OFF + N;                 // N   deg_in^-1/2
constexpr size_t EL_OFF   = NI_OFF + N;                 // N+1 GAT el (incl supernode)
constexpr size_t ER_OFF   = EL_OFF + (N+1);             // N   GAT er
constexpr size_t EE_OFF   = ER_OFF + N;                 // E   per-edge exp(e-m) (CSR order)
constexpr size_t IS_OFF   = EE_OFF + E;                 // N   1/softmax-denominator
constexpr size_t ASLF_OFF = IS_OFF + N;                 // N   self-loop numerator
constexpr size_t ASUP_OFF = ASLF_OFF + N;               // N   supernode-edge numerator
constexpr size_t GF = ((ASUP_OFF + N + 255)/256)*256;   // per-graph float count

// per-graph int block
constexpr size_t RP_OFF = 0;                            // N+1 row_ptr (CSR by dst)
constexpr size_t NX_OFF = RP_OFF + (N+1);               // N   fill cursor
constexpr size_t CT_OFF = NX_OFF + N;                   // N   in-degree count (excl self loop)
constexpr size_t SS_OFF = CT_OFF + N;                   // E   src sorted by dst
constexpr size_t GI = ((SS_OFF + E + 255)/256)*256;

// small region (after ints): roSum[3][64] at 0, roMax bits[3][64] at 192, scratch

__global__ __launch_bounds__(256) void k_init(float* fb, int* ib) {
  int idx = blockIdx.x*256 + threadIdx.x;
  if (idx < 3*N) {
    int g = idx / N, i = idx % N;
    fb[(size_t)g*GF + NO_OFF + i] = 1.0f;   // self-loop out-degree
    ib[(size_t)g*GI + CT_OFF + i] = 0;
  }
}

__global__ __launch_bounds__(256) void k_count(float* fb, int* ib,
    const int* s0,const int* d0,const int* s1,const int* d1,const int* s2,const int* d2) {
  int e = blockIdx.x*256 + threadIdx.x;
  int g = blockIdx.y;
  if (e >= E) return;
  const int* s = g==0?s0:(g==1?s1:s2);
  const int* d = g==0?d0:(g==1?d1:d2);
  atomicAdd(&fb[(size_t)g*GF + NO_OFF + s[e]], 1.0f);
  atomicAdd(&ib[(size_t)g*GI + CT_OFF + d[e]], 1);
}

__global__ __launch_bounds__(1024) void k_prefix(float* fb, int* ib) {
  int g = blockIdx.x;
  float* fg = fb + (size_t)g*GF;
  int* ig = ib + (size_t)g*GI;
  const int* cnt = ig + CT_OFF;
  int* rp = ig + RP_OFF;
  int* nx = ig + NX_OFF;
  __shared__ int part[1024];
  int tid = threadIdx.x;
  const int CH = (N + 1023)/1024;
  int base = tid*CH;
  int s = 0;
  for (int i=0;i<CH;i++){ int idx=base+i; if (idx<N) s += cnt[idx]; }
  int own = s;
  part[tid] = s; __syncthreads();
  for (int off=1; off<1024; off<<=1){
    int v = (tid>=off) ? part[tid-off] : 0;
    __syncthreads();
    part[tid] += v;
    __syncthreads();
  }
  int run = part[tid] - own;           // exclusive
  for (int i=0;i<CH;i++){
    int idx = base+i;
    if (idx<N){
      int c = cnt[idx];
      rp[idx] = run; nx[idx] = run;
      fg[NI_OFF+idx] = rsqrtf((float)(c+1));        // +1 self loop
      fg[NO_OFF+idx] = rsqrtf(fg[NO_OFF+idx]);      // already includes +1
      run += c;
    }
  }
  if (tid==1023) rp[N] = part[1023];
}

__global__ __launch_bounds__(256) void k_scatter(int* ib,
    const int* s0,const int* d0,const int* s1,const int* d1,const int* s2,const int* d2) {
  int e = blockIdx.x*256 + threadIdx.x;
  int g = blockIdx.y;
  if (e >= E) return;
  const int* s = g==0?s0:(g==1?s1:s2);
  const int* d = g==0?d0:(g==1?d1:d2);
  int* ig = ib + (size_t)g*GI;
  int pos = atomicAdd(&ig[NX_OFF + d[e]], 1);
  ig[SS_OFF + pos] = s[e];
}

__global__ __launch_bounds__(256) void k_copyx(float* fb, const float* x0,const float* x1,const float* x2) {
  int i = blockIdx.x*256 + threadIdx.x;
  int g = blockIdx.y;
  const float* x = g==0?x0:(g==1?x1:x2);
  if (i < N*H/4) {
    ((float4*)(fb + (size_t)g*GF + X_OFF))[i] = ((const float4*)x)[i];
  }
}

// h = x @ W  (N rows), W in LDS
__global__ __launch_bounds__(256) void k_mm_gcn(float* fb, const float* W0,const float* W1,const float* W2) {
  int g = blockIdx.y;
  const float* W = g==0?W0:(g==1?W1:W2);
  __shared__ float Ws[64*64];
  for (int i=threadIdx.x; i<4096; i+=256) Ws[i] = W[i];
  __syncthreads();
  int row = blockIdx.x*256 + threadIdx.x;
  if (row >= N) return;
  float* fg = fb + (size_t)g*GF;
  const float4* x4 = (const float4*)(fg + X_OFF + (size_t)row*H);
  float4 xr[16];
  #pragma unroll
  for (int k=0;k<16;k++) xr[k] = x4[k];
  float acc[64];
  #pragma unroll
  for (int j=0;j<64;j++) acc[j] = 0.f;
  const float* xs = (const float*)xr;
  #pragma unroll
  for (int k=0;k<64;k++){
    float xk = xs[k];
    #pragma unroll
    for (int j=0;j<64;j++) acc[j] = fmaf(xk, Ws[k*64+j], acc[j]);
  }
  float4* h4 = (float4*)(fg + HB_OFF + (size_t)row*H);
  #pragma unroll
  for (int j=0;j<16;j++) h4[j] = ((const float4*)acc)[j];
}

// h = x @ Wgat[g], plus el = h.a_l, er = h.a_r
__global__ __launch_bounds__(256) void k_mm_gat(float* fb, const float* Wgat, const float* al, const float* ar) {
  int g = blockIdx.y;
  const float* W = Wgat + (size_t)g*4096;
  __shared__ float Ws[64*64];
  __shared__ float als[64], ars[64];
  for (int i=threadIdx.x; i<4096; i+=256) Ws[i] = W[i];
  if (threadIdx.x < 64){ als[threadIdx.x] = al[g*64+threadIdx.x]; ars[threadIdx.x] = ar[g*64+threadIdx.x]; }
  __syncthreads();
  int row = blockIdx.x*256 + threadIdx.x;
  if (row >= N) return;
  float* fg = fb + (size_t)g*GF;
  const float4* x4 = (const float4*)(fg + X_OFF + (size_t)row*H);
  float4 xr[16];
  #pragma unroll
  for (int k=0;k<16;k++) xr[k] = x4[k];
  float acc[64];
  #pragma unroll
  for (int j=0;j<64;j++) acc[j] = 0.f;
  const float* xs = (const float*)xr;
  #pragma unroll
  for (int k=0;k<64;k++){
    float xk = xs[k];
    #pragma unroll
    for (int j=0;j<64;j++) acc[j] = fmaf(xk, Ws[k*64+j], acc[j]);
  }
  float4* h4 = (float4*)(fg + HB_OFF + (size_t)row*H);
  #pragma unroll
  for (int j=0;j<16;j++) h4[j] = ((const float4*)acc)[j];
  float el = 0.f, er = 0.f;
  #pragma unroll
  for (int j=0;j<64;j++){ el = fmaf(acc[j], als[j], el); er = fmaf(acc[j], ars[j], er); }
  fg[EL_OFF + row] = el;
  fg[ER_OFF + row] = er;
}

// GCN aggregate + bias + relu -> new x ; fused mean/max readout
__global__ __launch_bounds__(256) void k_gcn_agg(float* fb, const int* ib,
    const float* b0, const float* b1, const float* b2, float* sm) {
  int g = blockIdx.y;
  const float* b = g==0?b0:(g==1?b1:b2);
  float* fg = fb + (size_t)g*GF;
  const int* ig = ib + (size_t)g*GI;
  int wave = threadIdx.x >> 6, lane = threadIdx.x & 63;
  int node = blockIdx.x*4 + wave;
  float v = 0.f;
  const float* h = fg + HB_OFF;
  const float* no = fg + NO_OFF;
  const int* rp = ig + RP_OFF;
  const int* ss = ig + SS_OFF;
  if (node < N){
    float acc = h[(size_t)node*64 + lane] * no[node];   // self loop
    int s0 = rp[node], s1 = rp[node+1];
    for (int k=s0; k<s1; k++){
      int s = ss[k];
      acc = fmaf(no[s], h[(size_t)s*64 + lane], acc);
    }
    v = acc * fg[NI_OFF+node] + b[lane];
    v = v > 0.f ? v : 0.f;
    fg[X_OFF + (size_t)node*64 + lane] = v;
  }
  __shared__ float sred[256];
  sred[threadIdx.x] = v;
  __syncthreads();
  if (threadIdx.x < 64){
    float s = sred[lane] + sred[64+lane] + sred[128+lane] + sred[192+lane];
    float mx = fmaxf(fmaxf(sred[lane], sred[64+lane]), fmaxf(sred[128+lane], sred[192+lane]));
    atomicAdd(&sm[g*64 + lane], s);
    atomicMax((int*)sm + 192 + g*64 + lane, __float_as_int(mx));  // v>=0 so int order == float order
  }
}

__global__ void k_zero_ro(float* sm) {
  int i = threadIdx.x;
  if (i < 384) sm[i] = 0.f;
}

// readout finalize + cross-graph feature exchange + supernode h row, el[N]
__global__ void k_exchange(float* fb, float* sm, const float* Wx, const float* bx,
                           const float* Wgat, const float* al, int it) {
  int gt = blockIdx.x;     // target graph
  int t = threadIdx.x;     // 64 threads
  int src, widx;
  if ((it & 1) == 0){ src = (gt==0)?1:(gt==1)?2:0; widx = (gt==0)?1:(gt==1)?0:2; }
  else              { src = (gt==0)?2:(gt==1)?0:1; widx = (gt==0)?5:(gt==1)?3:4; }
  __shared__ float ro[128];
  __shared__ float f[64];
  __shared__ float red[64];
  ro[t]      = sm[src*64 + t] * (1.0f/(float)N);
  ro[64 + t] = __int_as_float(((int*)sm)[192 + src*64 + t]);
  __syncthreads();
  float a = bx[widx*64 + t];
  for (int k=0;k<128;k++) a = fmaf(ro[k], Wx[(size_t)widx*8192 + k*64 + t], a);
  a = a > 0.f ? a : 0.f;
  f[t] = a;
  __syncthreads();
  float* fg = fb + (size_t)gt*GF;
  float hs = 0.f;
  for (int k=0;k<64;k++) hs = fmaf(f[k], Wgat[(size_t)gt*4096 + k*64 + t], hs);
  fg[HB_OFF + (size_t)N*64 + t] = hs;        // supernode h row
  red[t] = hs * al[gt*64 + t];
  __syncthreads();
  if (t == 0){
    float e = 0.f;
    for (int k=0;k<64;k++) e += red[k];
    fg[EL_OFF + N] = e;                      // el for supernode
  }
}

// per-dst softmax prep: store exp(e-m) per CSR edge, denominators, self/sup numerators
__global__ __launch_bounds__(256) void k_gat_prep(float* fb, const int* ib) {
  int i = blockIdx.x*256 + threadIdx.x;
  int g = blockIdx.y;
  if (i >= N) return;
  float* fg = fb + (size_t)g*GF;
  const int* ig = ib + (size_t)g*GI;
  const int* rp = ig + RP_OFF;
  const int* ss = ig + SS_OFF;
  const float* el = fg + EL_OFF;
  float eri = fg[ER_OFF + i];
  float* ee = fg + EE_OFF;
  float elsup = el[N];
  int s0 = rp[i], s1 = rp[i+1];
  auto lk = [](float x){ return x >= 0.f ? x : 0.2f*x; };
  float eself = lk(el[i] + eri);
  float esup  = lk(elsup + eri);
  float m = fmaxf(eself, esup);
  for (int k=s0; k<s1; k++){
    float e = lk(el[ss[k]] + eri);
    ee[k] = e;
    m = fmaxf(m, e);
  }
  float s = 0.f;
  for (int k=s0; k<s1; k++){
    float t = __expf(ee[k] - m);
    ee[k] = t;
    s += t;
  }
  float tself = __expf(eself - m), tsup = __expf(esup - m);
  s += tself + tsup;
  fg[IS_OFF + i]   = 1.0f / s;
  fg[ASLF_OFF + i] = tself;
  fg[ASUP_OFF + i] = tsup;
}

// GAT weighted aggregation -> new x
__global__ __launch_bounds__(256) void k_gat_agg(float* fb, const int* ib, const float* bgat) {
  int g = blockIdx.y;
  float* fg = fb + (size_t)g*GF;
  const int* ig = ib + (size_t)g*GI;
  int wave = threadIdx.x >> 6, lane = threadIdx.x & 63;
  int node = blockIdx.x*4 + wave;
  if (node >= N) return;
  const int* rp = ig + RP_OFF;
  const int* ss = ig + SS_OFF;
  const float* h = fg + HB_OFF;
  const float* ee = fg + EE_OFF;
  float acc = fg[ASLF_OFF+node] * h[(size_t)node*64 + lane]
            + fg[ASUP_OFF+node] * h[(size_t)N*64 + lane];
  int s0 = rp[node], s1 = rp[node+1];
  for (int k=s0; k<s1; k++){
    int s = ss[k];
    acc = fmaf(ee[k], h[(size_t)s*64 + lane], acc);
  }
  fg[X_OFF + (size_t)node*64 + lane] = acc * fg[IS_OFF+node] + bgat[g*64 + lane];
}

__global__ __launch_bounds__(384) void k_mlp(const float* sm, const float* W1, const float* b1,
    const float* W2, const float* b2, const float* W3, const float* b3, float* out) {
  __shared__ float nf[384];
  __shared__ float y1[192];
  __shared__ float y2[96];
  __shared__ float z[2];
  int t = threadIdx.x;
  int g = t / 128, j = t % 128;
  nf[t] = (j < 64) ? sm[g*64 + j] * (1.0f/(float)N)
                   : __int_as_float(((const int*)sm)[192 + g*64 + (j-64)]);
  __syncthreads();
  if (t < 192){
    float a = b1[t];
    for (int k=0;k<384;k++) a = fmaf(nf[k], W1[(size_t)k*192 + t], a);
    y1[t] = a > 0.f ? a : 0.f;
  }
  __syncthreads();
  if (t < 96){
    float a = b2[t];
    for (int k=0;k<192;k++) a = fmaf(y1[k], W2[(size_t)k*96 + t], a);
    y2[t] = a > 0.f ? a : 0.f;
  }
  __syncthreads();
  if (t < 2){
    float a = b3[t];
    for (int k=0;k<96;k++) a = fmaf(y2[k], W3[k*2 + t], a);
    z[t] = a;
  }
  __syncthreads();
  if (t == 0){
    float m = fmaxf(z[0], z[1]);
    float l = m + logf(__expf(z[0]-m) + __expf(z[1]-m));
    out[0] = z[0] - l;
    out[1] = z[1] - l;
  }
}

extern "C" void kernel_launch(void* const* d_in, const int* in_sizes, int n_in,
                              void* d_out, int out_size, void* d_ws, size_t ws_size,
                              hipStream_t stream) {
  const float* x_s  = (const float*)d_in[0];
  const float* x_g  = (const float*)d_in[1];
  const float* x_t  = (const float*)d_in[2];
  const float* Wc_s = (const float*)d_in[3];
  const float* bc_s = (const float*)d_in[4];
  const float* Wc_g = (const float*)d_in[5];
  const float* bc_g = (const float*)d_in[6];
  const float* Wc_t = (const float*)d_in[7];
  const float* bc_t = (const float*)d_in[8];
  const float* Wx   = (const float*)d_in[9];
  const float* bx   = (const float*)d_in[10];
  const float* Wgat = (const float*)d_in[11];
  const float* al   = (const float*)d_in[12];
  const float* ar   = (const float*)d_in[13];
  const float* bgat = (const float*)d_in[14];
  const float* W1   = (const float*)d_in[15];
  const float* b1   = (const float*)d_in[16];
  const float* W2   = (const float*)d_in[17];
  const float* b2   = (const float*)d_in[18];
  const float* W3   = (const float*)d_in[19];
  const float* b3   = (const float*)d_in[20];
  const int* src_s  = (const int*)d_in[21];
  const int* dst_s  = (const int*)d_in[22];
  const int* src_g  = (const int*)d_in[23];
  const int* dst_g  = (const int*)d_in[24];
  const int* src_t  = (const int*)d_in[25];
  const int* dst_t  = (const int*)d_in[26];

  float* fb = (float*)d_ws;
  int*   ib = (int*)(fb + 3*GF);
  float* sm = (float*)(ib + 3*GI);
  float* out = (float*)d_out;

  dim3 b256(256);

  // graph prep (CSR by dst + symmetric-norm degree vectors)
  k_init   <<<dim3((3*N+255)/256),      b256, 0, stream>>>(fb, ib);
  k_count  <<<dim3((E+255)/256, 3),     b256, 0, stream>>>(fb, ib, src_s,dst_s, src_g,dst_g, src_t,dst_t);
  k_prefix <<<dim3(3),            dim3(1024), 0, stream>>>(fb, ib);
  k_scatter<<<dim3((E+255)/256, 3),     b256, 0, stream>>>(ib, src_s,dst_s, src_g,dst_g, src_t,dst_t);
  k_copyx  <<<dim3((N*H/4+255)/256, 3), b256, 0, stream>>>(fb, x_s, x_g, x_t);

  for (int it = 0; it < 2; ++it) {
    k_zero_ro <<<1, 384, 0, stream>>>(sm);
    k_mm_gcn  <<<dim3((N+255)/256, 3), b256, 0, stream>>>(fb, Wc_s + it*4096, Wc_g + it*4096, Wc_t + it*4096);
    k_gcn_agg <<<dim3((N+3)/4, 3),     b256, 0, stream>>>(fb, ib, bc_s + it*64, bc_g + it*64, bc_t + it*64, sm);
    k_exchange<<<dim3(3), dim3(64), 0, stream>>>(fb, sm, Wx, bx, Wgat, al, it);
    k_mm_gat  <<<dim3((N+255)/256, 3), b256, 0, stream>>>(fb, Wgat, al, ar);
    k_gat_prep<<<dim3((N+255)/256, 3), b256, 0, stream>>>(fb, ib);
    k_gat_agg <<<dim3((N+3)/4, 3),     b256, 0, stream>>>(fb, ib, bgat);
  }

  // final layer readouts + MLP head
  k_zero_ro <<<1, 384, 0, stream>>>(sm);
  k_mm_gcn  <<<dim3((N+255)/256, 3), b256, 0, stream>>>(fb, Wc_s + 2*4096, Wc_g + 2*4096, Wc_t + 2*4096);
  k_gcn_agg <<<dim3((N+3)/4, 3),     b256, 0, stream>>>(fb, ib, bc_s + 2*64, bc_g + 2*64, bc_t + 2*64, sm);
  k_mlp     <<<1, 384, 0, stream>>>(sm, W1, b1, W2, b2, W3, b3, out);
}

// Round 2
// 2886.397 us; speedup vs baseline: 1.1650x; 1.1650x over previous
//
#include <hip/hip_runtime.h>
#include <math.h>

constexpr int N = 50000;
constexpr int E = 800000;
constexpr int H = 64;

// ---- workspace layout (element offsets) ----
// per-graph float block
constexpr size_t X_OFF    = 0;                          // N*H   current node features
constexpr size_t HB_OFF   = X_OFF + (size_t)N*H;        // (N+1)*H  matmul output (row N = supernode)
constexpr size_t NO_OFF   = HB_OFF + (size_t)(N+1)*H;   // N   deg_out^-1/2
constexpr size_t NI_OFF   = NO_OFF + N;                 // N   deg_in^-1/2
constexpr size_t EL_OFF   = NI_OFF + N;                 // N+1 GAT el (incl supernode)
constexpr size_t ER_OFF   = EL_OFF + (N+1);             // N   GAT er
constexpr size_t EE_OFF   = ER_OFF + N;                 // E   per-edge exp(e-m) (CSR order)
constexpr size_t IS_OFF   = EE_OFF + E;                 // N   1/softmax-denominator
constexpr size_t ASLF_OFF = IS_OFF + N;                 // N   self-loop numerator
constexpr size_t ASUP_OFF = ASLF_OFF + N;               // N   supernode-edge numerator
constexpr size_t GF = ((ASUP_OFF + N + 255)/256)*256;   // per-graph float count

// per-graph int block
constexpr size_t RP_OFF = 0;                            // N+1 row_ptr (CSR by dst)
constexpr size_t NX_OFF = RP_OFF + (N+1);               // N   fill cursor
constexpr size_t CT_OFF = NX_OFF + N;                   // N   in-degree count (excl self loop)
constexpr size_t SS_OFF = CT_OFF + N;                   // E   src sorted by dst
constexpr size_t GI = ((SS_OFF + E + 255)/256)*256;

// small region (after ints): roSum[3][64] at 0, roMax bits[3][64] at 192

__global__ __launch_bounds__(256) void k_init(float* fb, int* ib) {
  int idx = blockIdx.x*256 + threadIdx.x;
  if (idx < 3*N) {
    int g = idx / N, i = idx % N;
    fb[(size_t)g*GF + NO_OFF + i] = 1.0f;   // self-loop out-degree
    ib[(size_t)g*GI + CT_OFF + i] = 0;
  }
}

__global__ __launch_bounds__(256) void k_count(float* fb, int* ib,
    const int* s0,const int* d0,const int* s1,const int* d1,const int* s2,const int* d2) {
  int e = blockIdx.x*256 + threadIdx.x;
  int g = blockIdx.y;
  if (e >= E) return;
  const int* s = g==0?s0:(g==1?s1:s2);
  const int* d = g==0?d0:(g==1?d1:d2);
  atomicAdd(&fb[(size_t)g*GF + NO_OFF + s[e]], 1.0f);
  atomicAdd(&ib[(size_t)g*GI + CT_OFF + d[e]], 1);
}

__global__ __launch_bounds__(1024) void k_prefix(float* fb, int* ib) {
  int g = blockIdx.x;
  float* fg = fb + (size_t)g*GF;
  int* ig = ib + (size_t)g*GI;
  const int* cnt = ig + CT_OFF;
  int* rp = ig + RP_OFF;
  int* nx = ig + NX_OFF;
  __shared__ int part[1024];
  int tid = threadIdx.x;
  const int CH = (N + 1023)/1024;
  int base = tid*CH;
  int s = 0;
  for (int i=0;i<CH;i++){ int idx=base+i; if (idx<N) s += cnt[idx]; }
  int own = s;
  part[tid] = s; __syncthreads();
  for (int off=1; off<1024; off<<=1){
    int v = (tid>=off) ? part[tid-off] : 0;
    __syncthreads();
    part[tid] += v;
    __syncthreads();
  }
  int run = part[tid] - own;           // exclusive
  for (int i=0;i<CH;i++){
    int idx = base+i;
    if (idx<N){
      int c = cnt[idx];
      rp[idx] = run; nx[idx] = run;
      fg[NI_OFF+idx] = rsqrtf((float)(c+1));        // +1 self loop
      fg[NO_OFF+idx] = rsqrtf(fg[NO_OFF+idx]);      // already includes +1
      run += c;
    }
  }
  if (tid==1023) rp[N] = part[1023];
}

__global__ __launch_bounds__(256) void k_scatter(int* ib,
    const int* s0,const int* d0,const int* s1,const int* d1,const int* s2,const int* d2) {
  int e = blockIdx.x*256 + threadIdx.x;
  int g = blockIdx.y;
  if (e >= E) return;
  const int* s = g==0?s0:(g==1?s1:s2);
  const int* d = g==0?d0:(g==1?d1:d2);
  int* ig = ib + (size_t)g*GI;
  int pos = atomicAdd(&ig[NX_OFF + d[e]], 1);
  ig[SS_OFF + pos] = s[e];
}

__global__ __launch_bounds__(256) void k_copyx(float* fb, const float* x0,const float* x1,const float* x2) {
  int i = blockIdx.x*256 + threadIdx.x;
  int g = blockIdx.y;
  const float* x = g==0?x0:(g==1?x1:x2);
  if (i < N*H/4) {
    ((float4*)(fb + (size_t)g*GF + X_OFF))[i] = ((const float4*)x)[i];
  }
}

// h = (x @ W) * no[row]  (N rows), W in LDS.  no-prescale folds the GCN
// source normalization out of the aggregation hot loop.
__global__ __launch_bounds__(256) void k_mm_gcn(float* fb, const float* W0,const float* W1,const float* W2) {
  int g = blockIdx.y;
  const float* W = g==0?W0:(g==1?W1:W2);
  __shared__ float Ws[64*64];
  for (int i=threadIdx.x; i<4096; i+=256) Ws[i] = W[i];
  __syncthreads();
  int row = blockIdx.x*256 + threadIdx.x;
  if (row >= N) return;
  float* fg = fb + (size_t)g*GF;
  const float4* x4 = (const float4*)(fg + X_OFF + (size_t)row*H);
  float4 xr[16];
  #pragma unroll
  for (int k=0;k<16;k++) xr[k] = x4[k];
  float acc[64];
  #pragma unroll
  for (int j=0;j<64;j++) acc[j] = 0.f;
  const float* xs = (const float*)xr;
  #pragma unroll
  for (int k=0;k<64;k++){
    float xk = xs[k];
    #pragma unroll
    for (int j=0;j<64;j++) acc[j] = fmaf(xk, Ws[k*64+j], acc[j]);
  }
  float sc = fg[NO_OFF + row];
  #pragma unroll
  for (int j=0;j<64;j++) acc[j] *= sc;
  float4* h4 = (float4*)(fg + HB_OFF + (size_t)row*H);
  #pragma unroll
  for (int j=0;j<16;j++) h4[j] = ((const float4*)acc)[j];
}

// h = x @ Wgat[g], plus el = h.a_l, er = h.a_r
__global__ __launch_bounds__(256) void k_mm_gat(float* fb, const float* Wgat, const float* al, const float* ar) {
  int g = blockIdx.y;
  const float* W = Wgat + (size_t)g*4096;
  __shared__ float Ws[64*64];
  __shared__ float als[64], ars[64];
  for (int i=threadIdx.x; i<4096; i+=256) Ws[i] = W[i];
  if (threadIdx.x < 64){ als[threadIdx.x] = al[g*64+threadIdx.x]; ars[threadIdx.x] = ar[g*64+threadIdx.x]; }
  __syncthreads();
  int row = blockIdx.x*256 + threadIdx.x;
  if (row >= N) return;
  float* fg = fb + (size_t)g*GF;
  const float4* x4 = (const float4*)(fg + X_OFF + (size_t)row*H);
  float4 xr[16];
  #pragma unroll
  for (int k=0;k<16;k++) xr[k] = x4[k];
  float acc[64];
  #pragma unroll
  for (int j=0;j<64;j++) acc[j] = 0.f;
  const float* xs = (const float*)xr;
  #pragma unroll
  for (int k=0;k<64;k++){
    float xk = xs[k];
    #pragma unroll
    for (int j=0;j<64;j++) acc[j] = fmaf(xk, Ws[k*64+j], acc[j]);
  }
  float4* h4 = (float4*)(fg + HB_OFF + (size_t)row*H);
  #pragma unroll
  for (int j=0;j<16;j++) h4[j] = ((const float4*)acc)[j];
  float el = 0.f, er = 0.f;
  #pragma unroll
  for (int j=0;j<64;j++){ el = fmaf(acc[j], als[j], el); er = fmaf(acc[j], ars[j], er); }
  fg[EL_OFF + row] = el;
  fg[ER_OFF + row] = er;
}

// GCN aggregate + bias + relu -> new x ; fused mean/max readout.
// h rows are pre-scaled by no[src]; edge loop unrolled x8 so 8 gathers are
// in flight per wave (latency -> BW bound).
__global__ __launch_bounds__(256) void k_gcn_agg(float* fb, const int* ib,
    const float* b0, const float* b1, const float* b2, float* sm) {
  int g = blockIdx.y;
  const float* b = g==0?b0:(g==1?b1:b2);
  float* fg = fb + (size_t)g*GF;
  const int* ig = ib + (size_t)g*GI;
  int wave = threadIdx.x >> 6, lane = threadIdx.x & 63;
  int node = blockIdx.x*4 + wave;
  float v = 0.f;
  const float* h = fg + HB_OFF;
  const int* rp = ig + RP_OFF;
  const int* ss = ig + SS_OFF;
  if (node < N){
    float acc = h[(size_t)node*64 + lane];   // self loop (pre-scaled by no[node])
    int s0 = rp[node], s1 = rp[node+1];
    int k = s0;
    for (; k + 8 <= s1; k += 8){
      int i0=ss[k],i1=ss[k+1],i2=ss[k+2],i3=ss[k+3];
      int i4=ss[k+4],i5=ss[k+5],i6=ss[k+6],i7=ss[k+7];
      float v0=h[(size_t)i0*64+lane], v1=h[(size_t)i1*64+lane];
      float v2=h[(size_t)i2*64+lane], v3=h[(size_t)i3*64+lane];
      float v4=h[(size_t)i4*64+lane], v5=h[(size_t)i5*64+lane];
      float v6=h[(size_t)i6*64+lane], v7=h[(size_t)i7*64+lane];
      acc += ((v0+v1)+(v2+v3)) + ((v4+v5)+(v6+v7));
    }
    for (; k < s1; k++){
      acc += h[(size_t)ss[k]*64 + lane];
    }
    v = acc * fg[NI_OFF+node] + b[lane];
    v = v > 0.f ? v : 0.f;
    fg[X_OFF + (size_t)node*64 + lane] = v;
  }
  __shared__ float sred[256];
  sred[threadIdx.x] = v;
  __syncthreads();
  if (threadIdx.x < 64){
    float s = sred[lane] + sred[64+lane] + sred[128+lane] + sred[192+lane];
    float mx = fmaxf(fmaxf(sred[lane], sred[64+lane]), fmaxf(sred[128+lane], sred[192+lane]));
    atomicAdd(&sm[g*64 + lane], s);
    atomicMax((int*)sm + 192 + g*64 + lane, __float_as_int(mx));  // v>=0 so int order == float order
  }
}

__global__ void k_zero_ro(float* sm) {
  int i = threadIdx.x;
  if (i < 384) sm[i] = 0.f;
}

// readout finalize + cross-graph feature exchange + supernode h row, el[N]
__global__ void k_exchange(float* fb, float* sm, const float* Wx, const float* bx,
                           const float* Wgat, const float* al, int it) {
  int gt = blockIdx.x;     // target graph
  int t = threadIdx.x;     // 64 threads
  int src, widx;
  if ((it & 1) == 0){ src = (gt==0)?1:(gt==1)?2:0; widx = (gt==0)?1:(gt==1)?0:2; }
  else              { src = (gt==0)?2:(gt==1)?0:1; widx = (gt==0)?5:(gt==1)?3:4; }
  __shared__ float ro[128];
  __shared__ float f[64];
  __shared__ float red[64];
  ro[t]      = sm[src*64 + t] * (1.0f/(float)N);
  ro[64 + t] = __int_as_float(((int*)sm)[192 + src*64 + t]);
  __syncthreads();
  float a = bx[widx*64 + t];
  for (int k=0;k<128;k++) a = fmaf(ro[k], Wx[(size_t)widx*8192 + k*64 + t], a);
  a = a > 0.f ? a : 0.f;
  f[t] = a;
  __syncthreads();
  float* fg = fb + (size_t)gt*GF;
  float hs = 0.f;
  for (int k=0;k<64;k++) hs = fmaf(f[k], Wgat[(size_t)gt*4096 + k*64 + t], hs);
  fg[HB_OFF + (size_t)N*64 + t] = hs;        // supernode h row
  red[t] = hs * al[gt*64 + t];
  __syncthreads();
  if (t == 0){
    float e = 0.f;
    for (int k=0;k<64;k++) e += red[k];
    fg[EL_OFF + N] = e;                      // el for supernode
  }
}

// per-dst softmax prep: store exp(e-m) per CSR edge, denominators, self/sup numerators
__global__ __launch_bounds__(256) void k_gat_prep(float* fb, const int* ib) {
  int i = blockIdx.x*256 + threadIdx.x;
  int g = blockIdx.y;
  if (i >= N) return;
  float* fg = fb + (size_t)g*GF;
  const int* ig = ib + (size_t)g*GI;
  const int* rp = ig + RP_OFF;
  const int* ss = ig + SS_OFF;
  const float* el = fg + EL_OFF;
  float eri = fg[ER_OFF + i];
  float* ee = fg + EE_OFF;
  float elsup = el[N];
  int s0 = rp[i], s1 = rp[i+1];
  auto lk = [](float x){ return x >= 0.f ? x : 0.2f*x; };
  float eself = lk(el[i] + eri);
  float esup  = lk(elsup + eri);
  float m = fmaxf(eself, esup);
  int k = s0;
  for (; k + 4 <= s1; k += 4){
    int i0=ss[k],i1=ss[k+1],i2=ss[k+2],i3=ss[k+3];
    float e0=lk(el[i0]+eri), e1=lk(el[i1]+eri);
    float e2=lk(el[i2]+eri), e3=lk(el[i3]+eri);
    ee[k]=e0; ee[k+1]=e1; ee[k+2]=e2; ee[k+3]=e3;
    m = fmaxf(m, fmaxf(fmaxf(e0,e1), fmaxf(e2,e3)));
  }
  for (; k < s1; k++){
    float e = lk(el[ss[k]] + eri);
    ee[k] = e;
    m = fmaxf(m, e);
  }
  float s = 0.f;
  k = s0;
  for (; k + 4 <= s1; k += 4){
    float t0 = __expf(ee[k]-m),   t1 = __expf(ee[k+1]-m);
    float t2 = __expf(ee[k+2]-m), t3 = __expf(ee[k+3]-m);
    ee[k]=t0; ee[k+1]=t1; ee[k+2]=t2; ee[k+3]=t3;
    s += (t0+t1)+(t2+t3);
  }
  for (; k < s1; k++){
    float t = __expf(ee[k] - m);
    ee[k] = t;
    s += t;
  }
  float tself = __expf(eself - m), tsup = __expf(esup - m);
  s += tself + tsup;
  fg[IS_OFF + i]   = 1.0f / s;
  fg[ASLF_OFF + i] = tself;
  fg[ASUP_OFF + i] = tsup;
}

// GAT weighted aggregation -> new x ; edge loop unrolled x8 for MLP.
__global__ __launch_bounds__(256) void k_gat_agg(float* fb, const int* ib, const float* bgat) {
  int g = blockIdx.y;
  float* fg = fb + (size_t)g*GF;
  const int* ig = ib + (size_t)g*GI;
  int wave = threadIdx.x >> 6, lane = threadIdx.x & 63;
  int node = blockIdx.x*4 + wave;
  if (node >= N) return;
  const int* rp = ig + RP_OFF;
  const int* ss = ig + SS_OFF;
  const float* h = fg + HB_OFF;
  const float* ee = fg + EE_OFF;
  float acc = fg[ASLF_OFF+node] * h[(size_t)node*64 + lane]
            + fg[ASUP_OFF+node] * h[(size_t)N*64 + lane];
  int s0 = rp[node], s1 = rp[node+1];
  int k = s0;
  for (; k + 8 <= s1; k += 8){
    int i0=ss[k],i1=ss[k+1],i2=ss[k+2],i3=ss[k+3];
    int i4=ss[k+4],i5=ss[k+5],i6=ss[k+6],i7=ss[k+7];
    float w0=ee[k],w1=ee[k+1],w2=ee[k+2],w3=ee[k+3];
    float w4=ee[k+4],w5=ee[k+5],w6=ee[k+6],w7=ee[k+7];
    float a0 = fmaf(w0, h[(size_t)i0*64+lane], w1 * h[(size_t)i1*64+lane]);
    float a1 = fmaf(w2, h[(size_t)i2*64+lane], w3 * h[(size_t)i3*64+lane]);
    float a2 = fmaf(w4, h[(size_t)i4*64+lane], w5 * h[(size_t)i5*64+lane]);
    float a3 = fmaf(w6, h[(size_t)i6*64+lane], w7 * h[(size_t)i7*64+lane]);
    acc += (a0+a1)+(a2+a3);
  }
  for (; k < s1; k++){
    acc = fmaf(ee[k], h[(size_t)ss[k]*64 + lane], acc);
  }
  fg[X_OFF + (size_t)node*64 + lane] = acc * fg[IS_OFF+node] + bgat[g*64 + lane];
}

__global__ __launch_bounds__(384) void k_mlp(const float* sm, const float* W1, const float* b1,
    const float* W2, const float* b2, const float* W3, const float* b3, float* out) {
  __shared__ float nf[384];
  __shared__ float y1[192];
  __shared__ float y2[96];
  __shared__ float z[2];
  int t = threadIdx.x;
  int g = t / 128, j = t % 128;
  nf[t] = (j < 64) ? sm[g*64 + j] * (1.0f/(float)N)
                   : __int_as_float(((const int*)sm)[192 + g*64 + (j-64)]);
  __syncthreads();
  if (t < 192){
    float a = b1[t];
    for (int k=0;k<384;k++) a = fmaf(nf[k], W1[(size_t)k*192 + t], a);
    y1[t] = a > 0.f ? a : 0.f;
  }
  __syncthreads();
  if (t < 96){
    float a = b2[t];
    for (int k=0;k<192;k++) a = fmaf(y1[k], W2[(size_t)k*96 + t], a);
    y2[t] = a > 0.f ? a : 0.f;
  }
  __syncthreads();
  if (t < 2){
    float a = b3[t];
    for (int k=0;k<96;k++) a = fmaf(y2[k], W3[k*2 + t], a);
    z[t] = a;
  }
  __syncthreads();
  if (t == 0){
    float m = fmaxf(z[0], z[1]);
    float l = m + logf(__expf(z[0]-m) + __expf(z[1]-m));
    out[0] = z[0] - l;
    out[1] = z[1] - l;
  }
}

extern "C" void kernel_launch(void* const* d_in, const int* in_sizes, int n_in,
                              void* d_out, int out_size, void* d_ws, size_t ws_size,
                              hipStream_t stream) {
  const float* x_s  = (const float*)d_in[0];
  const float* x_g  = (const float*)d_in[1];
  const float* x_t  = (const float*)d_in[2];
  const float* Wc_s = (const float*)d_in[3];
  const float* bc_s = (const float*)d_in[4];
  const float* Wc_g = (const float*)d_in[5];
  const float* bc_g = (const float*)d_in[6];
  const float* Wc_t = (const float*)d_in[7];
  const float* bc_t = (const float*)d_in[8];
  const float* Wx   = (const float*)d_in[9];
  const float* bx   = (const float*)d_in[10];
  const float* Wgat = (const float*)d_in[11];
  const float* al   = (const float*)d_in[12];
  const float* ar   = (const float*)d_in[13];
  const float* bgat = (const float*)d_in[14];
  const float* W1   = (const float*)d_in[15];
  const float* b1   = (const float*)d_in[16];
  const float* W2   = (const float*)d_in[17];
  const float* b2   = (const float*)d_in[18];
  const float* W3   = (const float*)d_in[19];
  const float* b3   = (const float*)d_in[20];
  const int* src_s  = (const int*)d_in[21];
  const int* dst_s  = (const int*)d_in[22];
  const int* src_g  = (const int*)d_in[23];
  const int* dst_g  = (const int*)d_in[24];
  const int* src_t  = (const int*)d_in[25];
  const int* dst_t  = (const int*)d_in[26];

  float* fb = (float*)d_ws;
  int*   ib = (int*)(fb + 3*GF);
  float* sm = (float*)(ib + 3*GI);
  float* out = (float*)d_out;

  dim3 b256(256);

  // graph prep (CSR by dst + symmetric-norm degree vectors)
  k_init   <<<dim3((3*N+255)/256),      b256, 0, stream>>>(fb, ib);
  k_count  <<<dim3((E+255)/256, 3),     b256, 0, stream>>>(fb, ib, src_s,dst_s, src_g,dst_g, src_t,dst_t);
  k_prefix <<<dim3(3),            dim3(1024), 0, stream>>>(fb, ib);
  k_scatter<<<dim3((E+255)/256, 3),     b256, 0, stream>>>(ib, src_s,dst_s, src_g,dst_g, src_t,dst_t);
  k_copyx  <<<dim3((N*H/4+255)/256, 3), b256, 0, stream>>>(fb, x_s, x_g, x_t);

  for (int it = 0; it < 2; ++it) {
    k_zero_ro <<<1, 384, 0, stream>>>(sm);
    k_mm_gcn  <<<dim3((N+255)/256, 3), b256, 0, stream>>>(fb, Wc_s + it*4096, Wc_g + it*4096, Wc_t + it*4096);
    k_gcn_agg <<<dim3((N+3)/4, 3),     b256, 0, stream>>>(fb, ib, bc_s + it*64, bc_g + it*64, bc_t + it*64, sm);
    k_exchange<<<dim3(3), dim3(64), 0, stream>>>(fb, sm, Wx, bx, Wgat, al, it);
    k_mm_gat  <<<dim3((N+255)/256, 3), b256, 0, stream>>>(fb, Wgat, al, ar);
    k_gat_prep<<<dim3((N+255)/256, 3), b256, 0, stream>>>(fb, ib);
    k_gat_agg <<<dim3((N+3)/4, 3),     b256, 0, stream>>>(fb, ib, bgat);
  }

  // final layer readouts + MLP head
  k_zero_ro <<<1, 384, 0, stream>>>(sm);
  k_mm_gcn  <<<dim3((N+255)/256, 3), b256, 0, stream>>>(fb, Wc_s + 2*4096, Wc_g + 2*4096, Wc_t + 2*4096);
  k_gcn_agg <<<dim3((N+3)/4, 3),     b256, 0, stream>>>(fb, ib, bc_s + 2*64, bc_g + 2*64, bc_t + 2*64, sm);
  k_mlp     <<<1, 384, 0, stream>>>(sm, W1, b1, W2, b2, W3, b3, out);
}

// Round 3
// 1846.174 us; speedup vs baseline: 1.8214x; 1.5634x over previous
//
#include <hip/hip_runtime.h>
#include <math.h>

constexpr int N = 50000;
constexpr int E = 800000;
constexpr int H = 64;
constexpr int NWAVE = 12500;          // N/4 nodes-per-wave mapping (4 nodes per wave)

typedef unsigned short ushort_t;
typedef unsigned int uint_t;

// ---- workspace layout (element offsets) ----
// per-graph float block (x stays fp32: feeds matmul)
constexpr size_t X_OFF    = 0;                          // N*H
constexpr size_t NO_OFF   = X_OFF + (size_t)N*H;        // N   deg_out^-1/2
constexpr size_t NI_OFF   = NO_OFF + N;                 // N   deg_in^-1/2
constexpr size_t EL_OFF   = NI_OFF + N;                 // N+1 GAT el (incl supernode)
constexpr size_t ER_OFF   = EL_OFF + (N+1);             // N   GAT er
constexpr size_t EE_OFF   = ER_OFF + N;                 // E   per-edge exp(e-m) (CSR order)
constexpr size_t IS_OFF   = EE_OFF + E;                 // N   1/softmax-denominator
constexpr size_t ASLF_OFF = IS_OFF + N;                 // N   self-loop numerator
constexpr size_t ASUP_OFF = ASLF_OFF + N;               // N   supernode numerator
constexpr size_t GF = ((ASUP_OFF + N + 255)/256)*256;

// per-graph int block
constexpr size_t RP_OFF = 0;                            // N+1 row_ptr (CSR by dst)
constexpr size_t NX_OFF = RP_OFF + (N+1);               // N   fill cursor
constexpr size_t CT_OFF = NX_OFF + N;                   // N   in-degree count
constexpr size_t SS_OFF = CT_OFF + N;                   // E   src sorted by dst
constexpr size_t GI = ((SS_OFF + E + 255)/256)*256;

// per-graph bf16 h block (row N = supernode), 64 ushorts per row
constexpr size_t GH = (size_t)(N+1)*64;

// bf16 helpers (RNE)
__device__ inline uint_t bfpack2(float a, float b){
  uint_t ua=__float_as_uint(a), ub=__float_as_uint(b);
  uint_t ra=(ua + 0x7fffu + ((ua>>16)&1u))>>16;
  uint_t rb=(ub + 0x7fffu + ((ub>>16)&1u))>>16;
  return ra | (rb<<16);
}
__device__ inline float bf2f(ushort_t u){ return __uint_as_float(((uint_t)u)<<16); }

__global__ __launch_bounds__(256) void k_init(float* fb, int* ib) {
  int idx = blockIdx.x*256 + threadIdx.x;
  if (idx < 3*N) {
    int g = idx / N, i = idx % N;
    fb[(size_t)g*GF + NO_OFF + i] = 1.0f;   // self-loop out-degree
    ib[(size_t)g*GI + CT_OFF + i] = 0;
  }
}

__global__ __launch_bounds__(256) void k_count(float* fb, int* ib,
    const int* s0,const int* d0,const int* s1,const int* d1,const int* s2,const int* d2) {
  int e = blockIdx.x*256 + threadIdx.x;
  int g = blockIdx.y;
  if (e >= E) return;
  const int* s = g==0?s0:(g==1?s1:s2);
  const int* d = g==0?d0:(g==1?d1:d2);
  atomicAdd(&fb[(size_t)g*GF + NO_OFF + s[e]], 1.0f);
  atomicAdd(&ib[(size_t)g*GI + CT_OFF + d[e]], 1);
}

__global__ __launch_bounds__(1024) void k_prefix(float* fb, int* ib) {
  int g = blockIdx.x;
  float* fg = fb + (size_t)g*GF;
  int* ig = ib + (size_t)g*GI;
  const int* cnt = ig + CT_OFF;
  int* rp = ig + RP_OFF;
  int* nx = ig + NX_OFF;
  __shared__ int part[1024];
  int tid = threadIdx.x;
  const int CH = (N + 1023)/1024;
  int base = tid*CH;
  int s = 0;
  for (int i=0;i<CH;i++){ int idx=base+i; if (idx<N) s += cnt[idx]; }
  int own = s;
  part[tid] = s; __syncthreads();
  for (int off=1; off<1024; off<<=1){
    int v = (tid>=off) ? part[tid-off] : 0;
    __syncthreads();
    part[tid] += v;
    __syncthreads();
  }
  int run = part[tid] - own;           // exclusive
  for (int i=0;i<CH;i++){
    int idx = base+i;
    if (idx<N){
      int c = cnt[idx];
      rp[idx] = run; nx[idx] = run;
      fg[NI_OFF+idx] = rsqrtf((float)(c+1));        // +1 self loop
      fg[NO_OFF+idx] = rsqrtf(fg[NO_OFF+idx]);      // already includes +1
      run += c;
    }
  }
  if (tid==1023) rp[N] = part[1023];
}

__global__ __launch_bounds__(256) void k_scatter(int* ib,
    const int* s0,const int* d0,const int* s1,const int* d1,const int* s2,const int* d2) {
  int e = blockIdx.x*256 + threadIdx.x;
  int g = blockIdx.y;
  if (e >= E) return;
  const int* s = g==0?s0:(g==1?s1:s2);
  const int* d = g==0?d0:(g==1?d1:d2);
  int* ig = ib + (size_t)g*GI;
  int pos = atomicAdd(&ig[NX_OFF + d[e]], 1);
  ig[SS_OFF + pos] = s[e];
}

__global__ __launch_bounds__(256) void k_copyx(float* fb, const float* x0,const float* x1,const float* x2) {
  int i = blockIdx.x*256 + threadIdx.x;
  int g = blockIdx.y;
  const float* x = g==0?x0:(g==1?x1:x2);
  if (i < N*H/4) {
    ((float4*)(fb + (size_t)g*GF + X_OFF))[i] = ((const float4*)x)[i];
  }
}

// h = bf16( (x @ W) * no[row] )  -> hb (gather operand, halved bytes)
__global__ __launch_bounds__(256) void k_mm_gcn(float* fb, ushort_t* hb,
    const float* W0,const float* W1,const float* W2) {
  int g = blockIdx.y;
  const float* W = g==0?W0:(g==1?W1:W2);
  __shared__ float Ws[64*64];
  for (int i=threadIdx.x; i<4096; i+=256) Ws[i] = W[i];
  __syncthreads();
  int row = blockIdx.x*256 + threadIdx.x;
  if (row >= N) return;
  float* fg = fb + (size_t)g*GF;
  const float4* x4 = (const float4*)(fg + X_OFF + (size_t)row*H);
  float4 xr[16];
  #pragma unroll
  for (int k=0;k<16;k++) xr[k] = x4[k];
  float acc[64];
  #pragma unroll
  for (int j=0;j<64;j++) acc[j] = 0.f;
  const float* xs = (const float*)xr;
  #pragma unroll
  for (int k=0;k<64;k++){
    float xk = xs[k];
    #pragma unroll
    for (int j=0;j<64;j++) acc[j] = fmaf(xk, Ws[k*64+j], acc[j]);
  }
  float sc = fg[NO_OFF + row];
  uint_t pk[32];
  #pragma unroll
  for (int j=0;j<32;j++) pk[j] = bfpack2(acc[2*j]*sc, acc[2*j+1]*sc);
  uint4* h4 = (uint4*)(hb + (size_t)g*GH + (size_t)row*64);
  #pragma unroll
  for (int j=0;j<8;j++) h4[j] = ((const uint4*)pk)[j];
}

// h = bf16(x @ Wgat[g]), el/er from fp32 acc
__global__ __launch_bounds__(256) void k_mm_gat(float* fb, ushort_t* hb,
    const float* Wgat, const float* al, const float* ar) {
  int g = blockIdx.y;
  const float* W = Wgat + (size_t)g*4096;
  __shared__ float Ws[64*64];
  __shared__ float als[64], ars[64];
  for (int i=threadIdx.x; i<4096; i+=256) Ws[i] = W[i];
  if (threadIdx.x < 64){ als[threadIdx.x] = al[g*64+threadIdx.x]; ars[threadIdx.x] = ar[g*64+threadIdx.x]; }
  __syncthreads();
  int row = blockIdx.x*256 + threadIdx.x;
  if (row >= N) return;
  float* fg = fb + (size_t)g*GF;
  const float4* x4 = (const float4*)(fg + X_OFF + (size_t)row*H);
  float4 xr[16];
  #pragma unroll
  for (int k=0;k<16;k++) xr[k] = x4[k];
  float acc[64];
  #pragma unroll
  for (int j=0;j<64;j++) acc[j] = 0.f;
  const float* xs = (const float*)xr;
  #pragma unroll
  for (int k=0;k<64;k++){
    float xk = xs[k];
    #pragma unroll
    for (int j=0;j<64;j++) acc[j] = fmaf(xk, Ws[k*64+j], acc[j]);
  }
  uint_t pk[32];
  #pragma unroll
  for (int j=0;j<32;j++) pk[j] = bfpack2(acc[2*j], acc[2*j+1]);
  uint4* h4 = (uint4*)(hb + (size_t)g*GH + (size_t)row*64);
  #pragma unroll
  for (int j=0;j<8;j++) h4[j] = ((const uint4*)pk)[j];
  float el = 0.f, er = 0.f;
  #pragma unroll
  for (int j=0;j<64;j++){ el = fmaf(acc[j], als[j], el); er = fmaf(acc[j], ars[j], er); }
  fg[EL_OFF + row] = el;
  fg[ER_OFF + row] = er;
}

// GCN aggregate + bias + relu -> new x ; fused mean/max readout.
// Per-graph dispatch; 4 nodes per wave (node = w + 12500*i).
__global__ __launch_bounds__(256) void k_gcn_agg(float* fb, const ushort_t* hb, const int* ib,
    const float* b, float* sm, int g) {
  float* fg = fb + (size_t)g*GF;
  const ushort_t* h = hb + (size_t)g*GH;
  const int* ig = ib + (size_t)g*GI;
  int wave = threadIdx.x >> 6, lane = threadIdx.x & 63;
  int w = blockIdx.x*4 + wave;
  const int* rp = ig + RP_OFF;
  const int* ss = ig + SS_OFF;
  float bl = b[lane];
  float vs = 0.f, vm = 0.f;
  #pragma unroll
  for (int i=0;i<4;i++){
    int node = w + NWAVE*i;
    if (node >= N) break;
    float acc = bf2f(h[(size_t)node*64 + lane]);   // self loop (pre-scaled)
    int s0 = rp[node], s1 = rp[node+1];
    int k = s0;
    for (; k + 8 <= s1; k += 8){
      int i0=ss[k],i1=ss[k+1],i2=ss[k+2],i3=ss[k+3];
      int i4=ss[k+4],i5=ss[k+5],i6=ss[k+6],i7=ss[k+7];
      float v0=bf2f(h[(size_t)i0*64+lane]), v1=bf2f(h[(size_t)i1*64+lane]);
      float v2=bf2f(h[(size_t)i2*64+lane]), v3=bf2f(h[(size_t)i3*64+lane]);
      float v4=bf2f(h[(size_t)i4*64+lane]), v5=bf2f(h[(size_t)i5*64+lane]);
      float v6=bf2f(h[(size_t)i6*64+lane]), v7=bf2f(h[(size_t)i7*64+lane]);
      acc += ((v0+v1)+(v2+v3)) + ((v4+v5)+(v6+v7));
    }
    for (; k < s1; k++) acc += bf2f(h[(size_t)ss[k]*64 + lane]);
    float v = acc * fg[NI_OFF+node] + bl;
    v = v > 0.f ? v : 0.f;
    fg[X_OFF + (size_t)node*64 + lane] = v;
    vs += v;
    vm = fmaxf(vm, v);
  }
  __shared__ float ssum[256];
  __shared__ float smax[256];
  ssum[threadIdx.x] = vs;
  smax[threadIdx.x] = vm;
  __syncthreads();
  if (threadIdx.x < 64){
    float s = ssum[lane] + ssum[64+lane] + ssum[128+lane] + ssum[192+lane];
    float mx = fmaxf(fmaxf(smax[lane], smax[64+lane]), fmaxf(smax[128+lane], smax[192+lane]));
    atomicAdd(&sm[g*64 + lane], s);
    atomicMax((int*)sm + 192 + g*64 + lane, __float_as_int(mx));  // v>=0: int order == float order
  }
}

__global__ void k_zero_ro(float* sm) {
  int i = threadIdx.x;
  if (i < 384) sm[i] = 0.f;
}

// readout finalize + cross-graph feature exchange + supernode h row (bf16), el[N]
__global__ void k_exchange(float* fb, ushort_t* hb, float* sm, const float* Wx, const float* bx,
                           const float* Wgat, const float* al, int it) {
  int gt = blockIdx.x;     // target graph
  int t = threadIdx.x;     // 64 threads
  int src, widx;
  if ((it & 1) == 0){ src = (gt==0)?1:(gt==1)?2:0; widx = (gt==0)?1:(gt==1)?0:2; }
  else              { src = (gt==0)?2:(gt==1)?0:1; widx = (gt==0)?5:(gt==1)?3:4; }
  __shared__ float ro[128];
  __shared__ float f[64];
  __shared__ float red[64];
  ro[t]      = sm[src*64 + t] * (1.0f/(float)N);
  ro[64 + t] = __int_as_float(((int*)sm)[192 + src*64 + t]);
  __syncthreads();
  float a = bx[widx*64 + t];
  for (int k=0;k<128;k++) a = fmaf(ro[k], Wx[(size_t)widx*8192 + k*64 + t], a);
  a = a > 0.f ? a : 0.f;
  f[t] = a;
  __syncthreads();
  float* fg = fb + (size_t)gt*GF;
  float hs = 0.f;
  for (int k=0;k<64;k++) hs = fmaf(f[k], Wgat[(size_t)gt*4096 + k*64 + t], hs);
  uint_t u = __float_as_uint(hs);
  hb[(size_t)gt*GH + (size_t)N*64 + t] = (ushort_t)((u + 0x7fffu + ((u>>16)&1u))>>16);
  red[t] = hs * al[gt*64 + t];
  __syncthreads();
  if (t == 0){
    float e = 0.f;
    for (int k=0;k<64;k++) e += red[k];
    fg[EL_OFF + N] = e;                      // el for supernode
  }
}

// per-dst softmax prep: store exp(e-m) per CSR edge, denominators, self/sup numerators
__global__ __launch_bounds__(256) void k_gat_prep(float* fb, const int* ib) {
  int i = blockIdx.x*256 + threadIdx.x;
  int g = blockIdx.y;
  if (i >= N) return;
  float* fg = fb + (size_t)g*GF;
  const int* ig = ib + (size_t)g*GI;
  const int* rp = ig + RP_OFF;
  const int* ss = ig + SS_OFF;
  const float* el = fg + EL_OFF;
  float eri = fg[ER_OFF + i];
  float* ee = fg + EE_OFF;
  float elsup = el[N];
  int s0 = rp[i], s1 = rp[i+1];
  auto lk = [](float x){ return x >= 0.f ? x : 0.2f*x; };
  float eself = lk(el[i] + eri);
  float esup  = lk(elsup + eri);
  float m = fmaxf(eself, esup);
  int k = s0;
  for (; k + 4 <= s1; k += 4){
    int i0=ss[k],i1=ss[k+1],i2=ss[k+2],i3=ss[k+3];
    float e0=lk(el[i0]+eri), e1=lk(el[i1]+eri);
    float e2=lk(el[i2]+eri), e3=lk(el[i3]+eri);
    ee[k]=e0; ee[k+1]=e1; ee[k+2]=e2; ee[k+3]=e3;
    m = fmaxf(m, fmaxf(fmaxf(e0,e1), fmaxf(e2,e3)));
  }
  for (; k < s1; k++){
    float e = lk(el[ss[k]] + eri);
    ee[k] = e;
    m = fmaxf(m, e);
  }
  float s = 0.f;
  k = s0;
  for (; k + 4 <= s1; k += 4){
    float t0 = __expf(ee[k]-m),   t1 = __expf(ee[k+1]-m);
    float t2 = __expf(ee[k+2]-m), t3 = __expf(ee[k+3]-m);
    ee[k]=t0; ee[k+1]=t1; ee[k+2]=t2; ee[k+3]=t3;
    s += (t0+t1)+(t2+t3);
  }
  for (; k < s1; k++){
    float t = __expf(ee[k] - m);
    ee[k] = t;
    s += t;
  }
  float tself = __expf(eself - m), tsup = __expf(esup - m);
  s += tself + tsup;
  fg[IS_OFF + i]   = 1.0f / s;
  fg[ASLF_OFF + i] = tself;
  fg[ASUP_OFF + i] = tsup;
}

// GAT weighted aggregation -> new x ; per-graph dispatch, 4 nodes per wave.
__global__ __launch_bounds__(256) void k_gat_agg(float* fb, const ushort_t* hb, const int* ib,
    const float* bgat, int g) {
  float* fg = fb + (size_t)g*GF;
  const ushort_t* h = hb + (size_t)g*GH;
  const int* ig = ib + (size_t)g*GI;
  int wave = threadIdx.x >> 6, lane = threadIdx.x & 63;
  int w = blockIdx.x*4 + wave;
  const int* rp = ig + RP_OFF;
  const int* ss = ig + SS_OFF;
  const float* ee = fg + EE_OFF;
  float sup = bf2f(h[(size_t)N*64 + lane]);
  float bl = bgat[g*64 + lane];
  #pragma unroll
  for (int i=0;i<4;i++){
    int node = w + NWAVE*i;
    if (node >= N) break;
    float acc = fg[ASLF_OFF+node] * bf2f(h[(size_t)node*64 + lane])
              + fg[ASUP_OFF+node] * sup;
    int s0 = rp[node], s1 = rp[node+1];
    int k = s0;
    for (; k + 8 <= s1; k += 8){
      int i0=ss[k],i1=ss[k+1],i2=ss[k+2],i3=ss[k+3];
      int i4=ss[k+4],i5=ss[k+5],i6=ss[k+6],i7=ss[k+7];
      float w0=ee[k],w1=ee[k+1],w2=ee[k+2],w3=ee[k+3];
      float w4=ee[k+4],w5=ee[k+5],w6=ee[k+6],w7=ee[k+7];
      float a0 = fmaf(w0, bf2f(h[(size_t)i0*64+lane]), w1 * bf2f(h[(size_t)i1*64+lane]));
      float a1 = fmaf(w2, bf2f(h[(size_t)i2*64+lane]), w3 * bf2f(h[(size_t)i3*64+lane]));
      float a2 = fmaf(w4, bf2f(h[(size_t)i4*64+lane]), w5 * bf2f(h[(size_t)i5*64+lane]));
      float a3 = fmaf(w6, bf2f(h[(size_t)i6*64+lane]), w7 * bf2f(h[(size_t)i7*64+lane]));
      acc += (a0+a1)+(a2+a3);
    }
    for (; k < s1; k++) acc = fmaf(ee[k], bf2f(h[(size_t)ss[k]*64 + lane]), acc);
    fg[X_OFF + (size_t)node*64 + lane] = acc * fg[IS_OFF+node] + bl;
  }
}

__global__ __launch_bounds__(384) void k_mlp(const float* sm, const float* W1, const float* b1,
    const float* W2, const float* b2, const float* W3, const float* b3, float* out) {
  __shared__ float nf[384];
  __shared__ float y1[192];
  __shared__ float y2[96];
  __shared__ float z[2];
  int t = threadIdx.x;
  int g = t / 128, j = t % 128;
  nf[t] = (j < 64) ? sm[g*64 + j] * (1.0f/(float)N)
                   : __int_as_float(((const int*)sm)[192 + g*64 + (j-64)]);
  __syncthreads();
  if (t < 192){
    float a = b1[t];
    for (int k=0;k<384;k++) a = fmaf(nf[k], W1[(size_t)k*192 + t], a);
    y1[t] = a > 0.f ? a : 0.f;
  }
  __syncthreads();
  if (t < 96){
    float a = b2[t];
    for (int k=0;k<192;k++) a = fmaf(y1[k], W2[(size_t)k*96 + t], a);
    y2[t] = a > 0.f ? a : 0.f;
  }
  __syncthreads();
  if (t < 2){
    float a = b3[t];
    for (int k=0;k<96;k++) a = fmaf(y2[k], W3[k*2 + t], a);
    z[t] = a;
  }
  __syncthreads();
  if (t == 0){
    float m = fmaxf(z[0], z[1]);
    float l = m + logf(__expf(z[0]-m) + __expf(z[1]-m));
    out[0] = z[0] - l;
    out[1] = z[1] - l;
  }
}

extern "C" void kernel_launch(void* const* d_in, const int* in_sizes, int n_in,
                              void* d_out, int out_size, void* d_ws, size_t ws_size,
                              hipStream_t stream) {
  const float* x_s  = (const float*)d_in[0];
  const float* x_g  = (const float*)d_in[1];
  const float* x_t  = (const float*)d_in[2];
  const float* Wc_s = (const float*)d_in[3];
  const float* bc_s = (const float*)d_in[4];
  const float* Wc_g = (const float*)d_in[5];
  const float* bc_g = (const float*)d_in[6];
  const float* Wc_t = (const float*)d_in[7];
  const float* bc_t = (const float*)d_in[8];
  const float* Wx   = (const float*)d_in[9];
  const float* bx   = (const float*)d_in[10];
  const float* Wgat = (const float*)d_in[11];
  const float* al   = (const float*)d_in[12];
  const float* ar   = (const float*)d_in[13];
  const float* bgat = (const float*)d_in[14];
  const float* W1   = (const float*)d_in[15];
  const float* b1   = (const float*)d_in[16];
  const float* W2   = (const float*)d_in[17];
  const float* b2   = (const float*)d_in[18];
  const float* W3   = (const float*)d_in[19];
  const float* b3   = (const float*)d_in[20];
  const int* src_s  = (const int*)d_in[21];
  const int* dst_s  = (const int*)d_in[22];
  const int* src_g  = (const int*)d_in[23];
  const int* dst_g  = (const int*)d_in[24];
  const int* src_t  = (const int*)d_in[25];
  const int* dst_t  = (const int*)d_in[26];

  float* fb = (float*)d_ws;
  int*   ib = (int*)(fb + 3*GF);
  ushort_t* hb = (ushort_t*)(ib + 3*GI);
  float* sm = (float*)(hb + 3*GH);
  float* out = (float*)d_out;

  dim3 b256(256);
  const float* bcs[3][3] = {{bc_s, bc_g, bc_t},{bc_s+64, bc_g+64, bc_t+64},{bc_s+128, bc_g+128, bc_t+128}};

  // graph prep (CSR by dst + symmetric-norm degree vectors)
  k_init   <<<dim3((3*N+255)/256),      b256, 0, stream>>>(fb, ib);
  k_count  <<<dim3((E+255)/256, 3),     b256, 0, stream>>>(fb, ib, src_s,dst_s, src_g,dst_g, src_t,dst_t);
  k_prefix <<<dim3(3),            dim3(1024), 0, stream>>>(fb, ib);
  k_scatter<<<dim3((E+255)/256, 3),     b256, 0, stream>>>(ib, src_s,dst_s, src_g,dst_g, src_t,dst_t);
  k_copyx  <<<dim3((N*H/4+255)/256, 3), b256, 0, stream>>>(fb, x_s, x_g, x_t);

  for (int it = 0; it < 2; ++it) {
    k_zero_ro <<<1, 384, 0, stream>>>(sm);
    k_mm_gcn  <<<dim3((N+255)/256, 3), b256, 0, stream>>>(fb, hb, Wc_s + it*4096, Wc_g + it*4096, Wc_t + it*4096);
    for (int g = 0; g < 3; ++g)
      k_gcn_agg <<<dim3(NWAVE/4), b256, 0, stream>>>(fb, hb, ib, bcs[it][g], sm, g);
    k_exchange<<<dim3(3), dim3(64), 0, stream>>>(fb, hb, sm, Wx, bx, Wgat, al, it);
    k_mm_gat  <<<dim3((N+255)/256, 3), b256, 0, stream>>>(fb, hb, Wgat, al, ar);
    k_gat_prep<<<dim3((N+255)/256, 3), b256, 0, stream>>>(fb, ib);
    for (int g = 0; g < 3; ++g)
      k_gat_agg <<<dim3(NWAVE/4), b256, 0, stream>>>(fb, hb, ib, bgat, g);
  }

  // final layer readouts + MLP head
  k_zero_ro <<<1, 384, 0, stream>>>(sm);
  k_mm_gcn  <<<dim3((N+255)/256, 3), b256, 0, stream>>>(fb, hb, Wc_s + 2*4096, Wc_g + 2*4096, Wc_t + 2*4096);
  for (int g = 0; g < 3; ++g)
    k_gcn_agg <<<dim3(NWAVE/4), b256, 0, stream>>>(fb, hb, ib, bcs[2][g], sm, g);
  k_mlp     <<<1, 384, 0, stream>>>(sm, W1, b1, W2, b2, W3, b3, out);
}

// Round 4
// 1630.226 us; speedup vs baseline: 2.0627x; 1.1325x over previous
//
#include <hip/hip_runtime.h>
#include <math.h>

constexpr int N = 50000;
constexpr int E = 800000;
constexpr int H = 64;
constexpr int NWAVE = 12500;          // N/4 nodes-per-wave mapping (4 nodes per wave)
constexpr int SCB = 49;               // scan blocks per graph: 49*1024 >= N

typedef unsigned short ushort_t;
typedef unsigned int uint_t;

// ---- workspace layout (element offsets) ----
// per-graph float block (x stays fp32: feeds matmul)
constexpr size_t X_OFF    = 0;                          // N*H
constexpr size_t NO_OFF   = X_OFF + (size_t)N*H;        // N   deg_out^-1/2
constexpr size_t NI_OFF   = NO_OFF + N;                 // N   deg_in^-1/2
constexpr size_t EL_OFF   = NI_OFF + N;                 // N+1 GAT el (incl supernode)
constexpr size_t ER_OFF   = EL_OFF + (N+1);             // N   GAT er
constexpr size_t EE_OFF   = ER_OFF + N;                 // E   per-edge exp(e-m) (CSR order)
constexpr size_t IS_OFF   = EE_OFF + E;                 // N   1/softmax-denominator
constexpr size_t ASLF_OFF = IS_OFF + N;                 // N   self-loop numerator
constexpr size_t ASUP_OFF = ASLF_OFF + N;               // N   supernode numerator
constexpr size_t GF = ((ASUP_OFF + N + 255)/256)*256;

// per-graph int block
constexpr size_t RP_OFF = 0;                            // N+1 row_ptr (CSR by dst)
constexpr size_t NX_OFF = RP_OFF + (N+1);               // N   fill cursor
constexpr size_t CT_OFF = NX_OFF + N;                   // N   in-degree count
constexpr size_t SS_OFF = CT_OFF + N;                   // E   src sorted by dst
constexpr size_t GI = ((SS_OFF + E + 255)/256)*256;

// per-graph bf16 h block (row N = supernode), 64 ushorts per row
constexpr size_t GH = (size_t)(N+1)*64;

// bf16 helpers (RNE)
__device__ inline uint_t bfpack2(float a, float b){
  uint_t ua=__float_as_uint(a), ub=__float_as_uint(b);
  uint_t ra=(ua + 0x7fffu + ((ua>>16)&1u))>>16;
  uint_t rb=(ub + 0x7fffu + ((ub>>16)&1u))>>16;
  return ra | (rb<<16);
}
__device__ inline float bf2f(ushort_t u){ return __uint_as_float(((uint_t)u)<<16); }

__global__ __launch_bounds__(256) void k_init(float* fb, int* ib) {
  int idx = blockIdx.x*256 + threadIdx.x;
  if (idx < 3*N) {
    int g = idx / N, i = idx % N;
    fb[(size_t)g*GF + NO_OFF + i] = 1.0f;   // self-loop out-degree
    ib[(size_t)g*GI + CT_OFF + i] = 0;
  }
}

__global__ __launch_bounds__(256) void k_count(float* fb, int* ib,
    const int* s0,const int* d0,const int* s1,const int* d1,const int* s2,const int* d2) {
  int e = blockIdx.x*256 + threadIdx.x;
  int g = blockIdx.y;
  if (e >= E) return;
  const int* s = g==0?s0:(g==1?s1:s2);
  const int* d = g==0?d0:(g==1?d1:d2);
  atomicAdd(&fb[(size_t)g*GF + NO_OFF + s[e]], 1.0f);
  atomicAdd(&ib[(size_t)g*GI + CT_OFF + d[e]], 1);
}

// ---- hierarchical exclusive scan of cnt -> rp (3 phases, all parallel) ----
__global__ __launch_bounds__(1024) void k_scan_local(int* ib, int* pt) {
  int g = blockIdx.y;
  int* ig = ib + (size_t)g*GI;
  const int* cnt = ig + CT_OFF;
  int i = blockIdx.x*1024 + threadIdx.x;
  int c = (i < N) ? cnt[i] : 0;
  __shared__ int sh[1024];
  sh[threadIdx.x] = c; __syncthreads();
  #pragma unroll
  for (int off=1; off<1024; off<<=1){
    int t = (threadIdx.x>=off) ? sh[threadIdx.x-off] : 0;
    __syncthreads();
    sh[threadIdx.x] += t;
    __syncthreads();
  }
  if (i < N) ig[RP_OFF + i] = sh[threadIdx.x] - c;       // local exclusive
  if (threadIdx.x == 1023) pt[g*SCB + blockIdx.x] = sh[1023];
}

__global__ void k_scan_part(int* pt) {
  int g = blockIdx.x;
  __shared__ int sh[SCB];
  int t = threadIdx.x;
  if (t < SCB) sh[t] = pt[g*SCB + t];
  __syncthreads();
  if (t == 0){
    int run = 0;
    for (int b=0;b<SCB;b++){ int c = sh[b]; sh[b] = run; run += c; }
  }
  __syncthreads();
  if (t < SCB) pt[g*SCB + t] = sh[t];
}

__global__ __launch_bounds__(1024) void k_scan_apply(float* fb, int* ib, const int* pt) {
  int g = blockIdx.y;
  float* fg = fb + (size_t)g*GF;
  int* ig = ib + (size_t)g*GI;
  int i = blockIdx.x*1024 + threadIdx.x;
  if (i >= N) return;
  int base = pt[g*SCB + blockIdx.x];
  int r = ig[RP_OFF + i] + base;
  ig[RP_OFF + i] = r;
  ig[NX_OFF + i] = r;
  int c = ig[CT_OFF + i];
  fg[NI_OFF + i] = rsqrtf((float)(c+1));                 // +1 self loop
  fg[NO_OFF + i] = rsqrtf(fg[NO_OFF + i]);               // count incl self loop
  if (i == N-1) ig[RP_OFF + N] = r + c;
}

__global__ __launch_bounds__(256) void k_scatter(int* ib,
    const int* s0,const int* d0,const int* s1,const int* d1,const int* s2,const int* d2) {
  int e = blockIdx.x*256 + threadIdx.x;
  int g = blockIdx.y;
  if (e >= E) return;
  const int* s = g==0?s0:(g==1?s1:s2);
  const int* d = g==0?d0:(g==1?d1:d2);
  int* ig = ib + (size_t)g*GI;
  int pos = atomicAdd(&ig[NX_OFF + d[e]], 1);
  ig[SS_OFF + pos] = s[e];
}

__global__ __launch_bounds__(256) void k_copyx(float* fb, const float* x0,const float* x1,const float* x2) {
  int i = blockIdx.x*256 + threadIdx.x;
  int g = blockIdx.y;
  const float* x = g==0?x0:(g==1?x1:x2);
  if (i < N*H/4) {
    ((float4*)(fb + (size_t)g*GF + X_OFF))[i] = ((const float4*)x)[i];
  }
}

// h = bf16( (x @ W) * no[row] )  -> hb (gather operand, halved bytes)
__global__ __launch_bounds__(256) void k_mm_gcn(float* fb, ushort_t* hb,
    const float* W0,const float* W1,const float* W2) {
  int g = blockIdx.y;
  const float* W = g==0?W0:(g==1?W1:W2);
  __shared__ float Ws[64*64];
  for (int i=threadIdx.x; i<4096; i+=256) Ws[i] = W[i];
  __syncthreads();
  int row = blockIdx.x*256 + threadIdx.x;
  if (row >= N) return;
  float* fg = fb + (size_t)g*GF;
  const float4* x4 = (const float4*)(fg + X_OFF + (size_t)row*H);
  float4 xr[16];
  #pragma unroll
  for (int k=0;k<16;k++) xr[k] = x4[k];
  float acc[64];
  #pragma unroll
  for (int j=0;j<64;j++) acc[j] = 0.f;
  const float* xs = (const float*)xr;
  #pragma unroll
  for (int k=0;k<64;k++){
    float xk = xs[k];
    #pragma unroll
    for (int j=0;j<64;j++) acc[j] = fmaf(xk, Ws[k*64+j], acc[j]);
  }
  float sc = fg[NO_OFF + row];
  uint_t pk[32];
  #pragma unroll
  for (int j=0;j<32;j++) pk[j] = bfpack2(acc[2*j]*sc, acc[2*j+1]*sc);
  uint4* h4 = (uint4*)(hb + (size_t)g*GH + (size_t)row*64);
  #pragma unroll
  for (int j=0;j<8;j++) h4[j] = ((const uint4*)pk)[j];
}

// h = bf16(x @ Wgat[g]), el/er from fp32 acc
__global__ __launch_bounds__(256) void k_mm_gat(float* fb, ushort_t* hb,
    const float* Wgat, const float* al, const float* ar) {
  int g = blockIdx.y;
  const float* W = Wgat + (size_t)g*4096;
  __shared__ float Ws[64*64];
  __shared__ float als[64], ars[64];
  for (int i=threadIdx.x; i<4096; i+=256) Ws[i] = W[i];
  if (threadIdx.x < 64){ als[threadIdx.x] = al[g*64+threadIdx.x]; ars[threadIdx.x] = ar[g*64+threadIdx.x]; }
  __syncthreads();
  int row = blockIdx.x*256 + threadIdx.x;
  if (row >= N) return;
  float* fg = fb + (size_t)g*GF;
  const float4* x4 = (const float4*)(fg + X_OFF + (size_t)row*H);
  float4 xr[16];
  #pragma unroll
  for (int k=0;k<16;k++) xr[k] = x4[k];
  float acc[64];
  #pragma unroll
  for (int j=0;j<64;j++) acc[j] = 0.f;
  const float* xs = (const float*)xr;
  #pragma unroll
  for (int k=0;k<64;k++){
    float xk = xs[k];
    #pragma unroll
    for (int j=0;j<64;j++) acc[j] = fmaf(xk, Ws[k*64+j], acc[j]);
  }
  uint_t pk[32];
  #pragma unroll
  for (int j=0;j<32;j++) pk[j] = bfpack2(acc[2*j], acc[2*j+1]);
  uint4* h4 = (uint4*)(hb + (size_t)g*GH + (size_t)row*64);
  #pragma unroll
  for (int j=0;j<8;j++) h4[j] = ((const uint4*)pk)[j];
  float el = 0.f, er = 0.f;
  #pragma unroll
  for (int j=0;j<64;j++){ el = fmaf(acc[j], als[j], el); er = fmaf(acc[j], ars[j], er); }
  fg[EL_OFF + row] = el;
  fg[ER_OFF + row] = er;
}

// GCN aggregate + bias + relu -> new x ; fused mean/max readout.
// Per-graph dispatch; 4 nodes per wave (node = w + 12500*i).
__global__ __launch_bounds__(256) void k_gcn_agg(float* fb, const ushort_t* hb, const int* ib,
    const float* b, float* sm, int g) {
  float* fg = fb + (size_t)g*GF;
  const ushort_t* h = hb + (size_t)g*GH;
  const int* ig = ib + (size_t)g*GI;
  int wave = threadIdx.x >> 6, lane = threadIdx.x & 63;
  int w = blockIdx.x*4 + wave;
  const int* rp = ig + RP_OFF;
  const int* ss = ig + SS_OFF;
  float bl = b[lane];
  float vs = 0.f, vm = 0.f;
  #pragma unroll
  for (int i=0;i<4;i++){
    int node = w + NWAVE*i;
    if (node >= N) break;
    float acc = bf2f(h[(size_t)node*64 + lane]);   // self loop (pre-scaled)
    int s0 = rp[node], s1 = rp[node+1];
    int k = s0;
    for (; k + 8 <= s1; k += 8){
      int i0=ss[k],i1=ss[k+1],i2=ss[k+2],i3=ss[k+3];
      int i4=ss[k+4],i5=ss[k+5],i6=ss[k+6],i7=ss[k+7];
      float v0=bf2f(h[(size_t)i0*64+lane]), v1=bf2f(h[(size_t)i1*64+lane]);
      float v2=bf2f(h[(size_t)i2*64+lane]), v3=bf2f(h[(size_t)i3*64+lane]);
      float v4=bf2f(h[(size_t)i4*64+lane]), v5=bf2f(h[(size_t)i5*64+lane]);
      float v6=bf2f(h[(size_t)i6*64+lane]), v7=bf2f(h[(size_t)i7*64+lane]);
      acc += ((v0+v1)+(v2+v3)) + ((v4+v5)+(v6+v7));
    }
    for (; k < s1; k++) acc += bf2f(h[(size_t)ss[k]*64 + lane]);
    float v = acc * fg[NI_OFF+node] + bl;
    v = v > 0.f ? v : 0.f;
    fg[X_OFF + (size_t)node*64 + lane] = v;
    vs += v;
    vm = fmaxf(vm, v);
  }
  __shared__ float ssum[256];
  __shared__ float smax[256];
  ssum[threadIdx.x] = vs;
  smax[threadIdx.x] = vm;
  __syncthreads();
  if (threadIdx.x < 64){
    float s = ssum[lane] + ssum[64+lane] + ssum[128+lane] + ssum[192+lane];
    float mx = fmaxf(fmaxf(smax[lane], smax[64+lane]), fmaxf(smax[128+lane], smax[192+lane]));
    atomicAdd(&sm[g*64 + lane], s);
    atomicMax((int*)sm + 192 + g*64 + lane, __float_as_int(mx));  // v>=0: int order == float order
  }
}

__global__ void k_zero_ro(float* sm) {
  int i = threadIdx.x;
  if (i < 384) sm[i] = 0.f;
}

// readout finalize + cross-graph feature exchange + supernode h row (bf16), el[N]
__global__ void k_exchange(float* fb, ushort_t* hb, float* sm, const float* Wx, const float* bx,
                           const float* Wgat, const float* al, int it) {
  int gt = blockIdx.x;     // target graph
  int t = threadIdx.x;     // 64 threads
  int src, widx;
  if ((it & 1) == 0){ src = (gt==0)?1:(gt==1)?2:0; widx = (gt==0)?1:(gt==1)?0:2; }
  else              { src = (gt==0)?2:(gt==1)?0:1; widx = (gt==0)?5:(gt==1)?3:4; }
  __shared__ float ro[128];
  __shared__ float f[64];
  __shared__ float red[64];
  ro[t]      = sm[src*64 + t] * (1.0f/(float)N);
  ro[64 + t] = __int_as_float(((int*)sm)[192 + src*64 + t]);
  __syncthreads();
  float a = bx[widx*64 + t];
  for (int k=0;k<128;k++) a = fmaf(ro[k], Wx[(size_t)widx*8192 + k*64 + t], a);
  a = a > 0.f ? a : 0.f;
  f[t] = a;
  __syncthreads();
  float* fg = fb + (size_t)gt*GF;
  float hs = 0.f;
  for (int k=0;k<64;k++) hs = fmaf(f[k], Wgat[(size_t)gt*4096 + k*64 + t], hs);
  uint_t u = __float_as_uint(hs);
  hb[(size_t)gt*GH + (size_t)N*64 + t] = (ushort_t)((u + 0x7fffu + ((u>>16)&1u))>>16);
  red[t] = hs * al[gt*64 + t];
  __syncthreads();
  if (t == 0){
    float e = 0.f;
    for (int k=0;k<64;k++) e += red[k];
    fg[EL_OFF + N] = e;                      // el for supernode
  }
}

// per-dst softmax prep: store exp(e-m) per CSR edge, denominators, self/sup numerators
__global__ __launch_bounds__(256) void k_gat_prep(float* fb, const int* ib) {
  int i = blockIdx.x*256 + threadIdx.x;
  int g = blockIdx.y;
  if (i >= N) return;
  float* fg = fb + (size_t)g*GF;
  const int* ig = ib + (size_t)g*GI;
  const int* rp = ig + RP_OFF;
  const int* ss = ig + SS_OFF;
  const float* el = fg + EL_OFF;
  float eri = fg[ER_OFF + i];
  float* ee = fg + EE_OFF;
  float elsup = el[N];
  int s0 = rp[i], s1 = rp[i+1];
  auto lk = [](float x){ return x >= 0.f ? x : 0.2f*x; };
  float eself = lk(el[i] + eri);
  float esup  = lk(elsup + eri);
  float m = fmaxf(eself, esup);
  int k = s0;
  for (; k + 4 <= s1; k += 4){
    int i0=ss[k],i1=ss[k+1],i2=ss[k+2],i3=ss[k+3];
    float e0=lk(el[i0]+eri), e1=lk(el[i1]+eri);
    float e2=lk(el[i2]+eri), e3=lk(el[i3]+eri);
    ee[k]=e0; ee[k+1]=e1; ee[k+2]=e2; ee[k+3]=e3;
    m = fmaxf(m, fmaxf(fmaxf(e0,e1), fmaxf(e2,e3)));
  }
  for (; k < s1; k++){
    float e = lk(el[ss[k]] + eri);
    ee[k] = e;
    m = fmaxf(m, e);
  }
  float s = 0.f;
  k = s0;
  for (; k + 4 <= s1; k += 4){
    float t0 = __expf(ee[k]-m),   t1 = __expf(ee[k+1]-m);
    float t2 = __expf(ee[k+2]-m), t3 = __expf(ee[k+3]-m);
    ee[k]=t0; ee[k+1]=t1; ee[k+2]=t2; ee[k+3]=t3;
    s += (t0+t1)+(t2+t3);
  }
  for (; k < s1; k++){
    float t = __expf(ee[k] - m);
    ee[k] = t;
    s += t;
  }
  float tself = __expf(eself - m), tsup = __expf(esup - m);
  s += tself + tsup;
  fg[IS_OFF + i]   = 1.0f / s;
  fg[ASLF_OFF + i] = tself;
  fg[ASUP_OFF + i] = tsup;
}

// GAT weighted aggregation -> new x ; per-graph dispatch, 4 nodes per wave.
__global__ __launch_bounds__(256) void k_gat_agg(float* fb, const ushort_t* hb, const int* ib,
    const float* bgat, int g) {
  float* fg = fb + (size_t)g*GF;
  const ushort_t* h = hb + (size_t)g*GH;
  const int* ig = ib + (size_t)g*GI;
  int wave = threadIdx.x >> 6, lane = threadIdx.x & 63;
  int w = blockIdx.x*4 + wave;
  const int* rp = ig + RP_OFF;
  const int* ss = ig + SS_OFF;
  const float* ee = fg + EE_OFF;
  float sup = bf2f(h[(size_t)N*64 + lane]);
  float bl = bgat[g*64 + lane];
  #pragma unroll
  for (int i=0;i<4;i++){
    int node = w + NWAVE*i;
    if (node >= N) break;
    float acc = fg[ASLF_OFF+node] * bf2f(h[(size_t)node*64 + lane])
              + fg[ASUP_OFF+node] * sup;
    int s0 = rp[node], s1 = rp[node+1];
    int k = s0;
    for (; k + 8 <= s1; k += 8){
      int i0=ss[k],i1=ss[k+1],i2=ss[k+2],i3=ss[k+3];
      int i4=ss[k+4],i5=ss[k+5],i6=ss[k+6],i7=ss[k+7];
      float w0=ee[k],w1=ee[k+1],w2=ee[k+2],w3=ee[k+3];
      float w4=ee[k+4],w5=ee[k+5],w6=ee[k+6],w7=ee[k+7];
      float a0 = fmaf(w0, bf2f(h[(size_t)i0*64+lane]), w1 * bf2f(h[(size_t)i1*64+lane]));
      float a1 = fmaf(w2, bf2f(h[(size_t)i2*64+lane]), w3 * bf2f(h[(size_t)i3*64+lane]));
      float a2 = fmaf(w4, bf2f(h[(size_t)i4*64+lane]), w5 * bf2f(h[(size_t)i5*64+lane]));
      float a3 = fmaf(w6, bf2f(h[(size_t)i6*64+lane]), w7 * bf2f(h[(size_t)i7*64+lane]));
      acc += (a0+a1)+(a2+a3);
    }
    for (; k < s1; k++) acc = fmaf(ee[k], bf2f(h[(size_t)ss[k]*64 + lane]), acc);
    fg[X_OFF + (size_t)node*64 + lane] = acc * fg[IS_OFF+node] + bl;
  }
}

__global__ __launch_bounds__(384) void k_mlp(const float* sm, const float* W1, const float* b1,
    const float* W2, const float* b2, const float* W3, const float* b3, float* out) {
  __shared__ float nf[384];
  __shared__ float y1[192];
  __shared__ float y2[96];
  __shared__ float z[2];
  int t = threadIdx.x;
  int g = t / 128, j = t % 128;
  nf[t] = (j < 64) ? sm[g*64 + j] * (1.0f/(float)N)
                   : __int_as_float(((const int*)sm)[192 + g*64 + (j-64)]);
  __syncthreads();
  if (t < 192){
    float a = b1[t];
    for (int k=0;k<384;k++) a = fmaf(nf[k], W1[(size_t)k*192 + t], a);
    y1[t] = a > 0.f ? a : 0.f;
  }
  __syncthreads();
  if (t < 96){
    float a = b2[t];
    for (int k=0;k<192;k++) a = fmaf(y1[k], W2[(size_t)k*96 + t], a);
    y2[t] = a > 0.f ? a : 0.f;
  }
  __syncthreads();
  if (t < 2){
    float a = b3[t];
    for (int k=0;k<96;k++) a = fmaf(y2[k], W3[k*2 + t], a);
    z[t] = a;
  }
  __syncthreads();
  if (t == 0){
    float m = fmaxf(z[0], z[1]);
    float l = m + logf(__expf(z[0]-m) + __expf(z[1]-m));
    out[0] = z[0] - l;
    out[1] = z[1] - l;
  }
}

extern "C" void kernel_launch(void* const* d_in, const int* in_sizes, int n_in,
                              void* d_out, int out_size, void* d_ws, size_t ws_size,
                              hipStream_t stream) {
  const float* x_s  = (const float*)d_in[0];
  const float* x_g  = (const float*)d_in[1];
  const float* x_t  = (const float*)d_in[2];
  const float* Wc_s = (const float*)d_in[3];
  const float* bc_s = (const float*)d_in[4];
  const float* Wc_g = (const float*)d_in[5];
  const float* bc_g = (const float*)d_in[6];
  const float* Wc_t = (const float*)d_in[7];
  const float* bc_t = (const float*)d_in[8];
  const float* Wx   = (const float*)d_in[9];
  const float* bx   = (const float*)d_in[10];
  const float* Wgat = (const float*)d_in[11];
  const float* al   = (const float*)d_in[12];
  const float* ar   = (const float*)d_in[13];
  const float* bgat = (const float*)d_in[14];
  const float* W1   = (const float*)d_in[15];
  const float* b1   = (const float*)d_in[16];
  const float* W2   = (const float*)d_in[17];
  const float* b2   = (const float*)d_in[18];
  const float* W3   = (const float*)d_in[19];
  const float* b3   = (const float*)d_in[20];
  const int* src_s  = (const int*)d_in[21];
  const int* dst_s  = (const int*)d_in[22];
  const int* src_g  = (const int*)d_in[23];
  const int* dst_g  = (const int*)d_in[24];
  const int* src_t  = (const int*)d_in[25];
  const int* dst_t  = (const int*)d_in[26];

  float* fb = (float*)d_ws;
  int*   ib = (int*)(fb + 3*GF);
  ushort_t* hb = (ushort_t*)(ib + 3*GI);
  float* sm = (float*)(hb + 3*GH);
  int*   pt = (int*)(sm + 384);          // 3*SCB scan partials
  float* out = (float*)d_out;

  dim3 b256(256);
  const float* bcs[3][3] = {{bc_s, bc_g, bc_t},{bc_s+64, bc_g+64, bc_t+64},{bc_s+128, bc_g+128, bc_t+128}};

  // graph prep (CSR by dst + symmetric-norm degree vectors)
  k_init      <<<dim3((3*N+255)/256),      b256, 0, stream>>>(fb, ib);
  k_count     <<<dim3((E+255)/256, 3),     b256, 0, stream>>>(fb, ib, src_s,dst_s, src_g,dst_g, src_t,dst_t);
  k_scan_local<<<dim3(SCB, 3),       dim3(1024), 0, stream>>>(ib, pt);
  k_scan_part <<<dim3(3),              dim3(64), 0, stream>>>(pt);
  k_scan_apply<<<dim3(SCB, 3),       dim3(1024), 0, stream>>>(fb, ib, pt);
  k_scatter   <<<dim3((E+255)/256, 3),     b256, 0, stream>>>(ib, src_s,dst_s, src_g,dst_g, src_t,dst_t);
  k_copyx     <<<dim3((N*H/4+255)/256, 3), b256, 0, stream>>>(fb, x_s, x_g, x_t);

  for (int it = 0; it < 2; ++it) {
    k_zero_ro <<<1, 384, 0, stream>>>(sm);
    k_mm_gcn  <<<dim3((N+255)/256, 3), b256, 0, stream>>>(fb, hb, Wc_s + it*4096, Wc_g + it*4096, Wc_t + it*4096);
    for (int g = 0; g < 3; ++g)
      k_gcn_agg <<<dim3(NWAVE/4), b256, 0, stream>>>(fb, hb, ib, bcs[it][g], sm, g);
    k_exchange<<<dim3(3), dim3(64), 0, stream>>>(fb, hb, sm, Wx, bx, Wgat, al, it);
    k_mm_gat  <<<dim3((N+255)/256, 3), b256, 0, stream>>>(fb, hb, Wgat, al, ar);
    k_gat_prep<<<dim3((N+255)/256, 3), b256, 0, stream>>>(fb, ib);
    for (int g = 0; g < 3; ++g)
      k_gat_agg <<<dim3(NWAVE/4), b256, 0, stream>>>(fb, hb, ib, bgat, g);
  }

  // final layer readouts + MLP head
  k_zero_ro <<<1, 384, 0, stream>>>(sm);
  k_mm_gcn  <<<dim3((N+255)/256, 3), b256, 0, stream>>>(fb, hb, Wc_s + 2*4096, Wc_g + 2*4096, Wc_t + 2*4096);
  for (int g = 0; g < 3; ++g)
    k_gcn_agg <<<dim3(NWAVE/4), b256, 0, stream>>>(fb, hb, ib, bcs[2][g], sm, g);
  k_mlp     <<<1, 384, 0, stream>>>(sm, W1, b1, W2, b2, W3, b3, out);
}

// Round 5
// 1350.542 us; speedup vs baseline: 2.4899x; 1.2071x over previous
//
#include <hip/hip_runtime.h>
#include <math.h>

constexpr int N = 50000;
constexpr int E = 800000;
constexpr int H = 64;
constexpr int NWAVE = 12500;          // N/4 nodes-per-wave mapping (4 nodes per wave)
constexpr int SCB = 49;               // scan blocks per graph: 49*1024 >= N
constexpr int RNG = 8;                // histogram ranges per graph
constexpr int BPR = 8;                // edge slices per graph
constexpr int BINS = N / RNG;         // 6250 bins per range
constexpr int ES   = E / BPR;         // 100000 edges per slice

typedef unsigned short ushort_t;
typedef unsigned int uint_t;

// ---- workspace layout (element offsets) ----
// per-graph float block (x stays fp32: feeds matmul)
constexpr size_t X_OFF    = 0;                          // N*H
constexpr size_t NO_OFF   = X_OFF + (size_t)N*H;        // N   deg_out^-1/2
constexpr size_t NI_OFF   = NO_OFF + N;                 // N   deg_in^-1/2
constexpr size_t EL_OFF   = NI_OFF + N;                 // N+1 GAT el (incl supernode)
constexpr size_t ER_OFF   = EL_OFF + (N+1);             // N   GAT er
constexpr size_t EE_OFF   = ER_OFF + N;                 // E   per-edge exp(e-m) (CSR order)
constexpr size_t IS_OFF   = EE_OFF + E;                 // N   1/softmax-denominator
constexpr size_t ASLF_OFF = IS_OFF + N;                 // N   self-loop numerator
constexpr size_t ASUP_OFF = ASLF_OFF + N;               // N   supernode numerator
constexpr size_t GF = ((ASUP_OFF + N + 255)/256)*256;

// per-graph int block
constexpr size_t RP_OFF = 0;                            // N+1 row_ptr (CSR by dst)
constexpr size_t CT_OFF = RP_OFF + (N+1);               // N   in-degree count
constexpr size_t SS_OFF = CT_OFF + N;                   // E   src sorted by dst
constexpr size_t GI = ((SS_OFF + E + 255)/256)*256;

// per-graph bf16 h block (row N = supernode), 64 ushorts per row
constexpr size_t GH = (size_t)(N+1)*64;

// bf16 helpers (RNE)
__device__ inline uint_t bfpack2(float a, float b){
  uint_t ua=__float_as_uint(a), ub=__float_as_uint(b);
  uint_t ra=(ua + 0x7fffu + ((ua>>16)&1u))>>16;
  uint_t rb=(ub + 0x7fffu + ((ub>>16)&1u))>>16;
  return ra | (rb<<16);
}
__device__ inline float bf2f(ushort_t u){ return __uint_as_float(((uint_t)u)<<16); }

// ---- prep: range-partitioned LDS histograms, zero global atomics ----
__global__ __launch_bounds__(1024) void k_hist(int* parts_ct, int* parts_no,
    const int* s0,const int* d0,const int* s1,const int* d1,const int* s2,const int* d2) {
  int sl = blockIdx.x, r = blockIdx.y, g = blockIdx.z;
  const int* s = g==0?s0:(g==1?s1:s2);
  const int* d = g==0?d0:(g==1?d1:d2);
  __shared__ int hc[BINS];
  __shared__ int hn[BINS];
  for (int i=threadIdx.x;i<BINS;i+=1024){ hc[i]=0; hn[i]=0; }
  __syncthreads();
  int lo = r*BINS, hi = lo+BINS;
  int e0 = sl*ES, e1 = e0+ES;
  for (int e=e0+threadIdx.x; e<e1; e+=1024){
    int ds = d[e], sr = s[e];
    if (ds>=lo && ds<hi) atomicAdd(&hc[ds-lo],1);
    if (sr>=lo && sr<hi) atomicAdd(&hn[sr-lo],1);
  }
  __syncthreads();
  size_t base = ((size_t)g*BPR + sl)*N + lo;
  for (int i=threadIdx.x;i<BINS;i+=1024){
    parts_ct[base+i]=hc[i];
    parts_no[base+i]=hn[i];
  }
}

// ---- hierarchical exclusive scan of cnt -> rp (all parallel) ----
__global__ __launch_bounds__(1024) void k_scan_local(int* ib, int* pt, const int* parts_ct) {
  int g = blockIdx.y;
  int* ig = ib + (size_t)g*GI;
  int i = blockIdx.x*1024 + threadIdx.x;
  int c = 0;
  if (i < N){
    #pragma unroll
    for (int s=0;s<BPR;s++) c += parts_ct[((size_t)g*BPR+s)*N + i];
    ig[CT_OFF + i] = c;
  }
  __shared__ int sh[1024];
  sh[threadIdx.x] = c; __syncthreads();
  #pragma unroll
  for (int off=1; off<1024; off<<=1){
    int t = (threadIdx.x>=off) ? sh[threadIdx.x-off] : 0;
    __syncthreads();
    sh[threadIdx.x] += t;
    __syncthreads();
  }
  if (i < N) ig[RP_OFF + i] = sh[threadIdx.x] - c;       // local exclusive
  if (threadIdx.x == 1023) pt[g*SCB + blockIdx.x] = sh[1023];
}

__global__ void k_scan_part(int* pt) {
  int g = blockIdx.x;
  __shared__ int sh[SCB];
  int t = threadIdx.x;
  if (t < SCB) sh[t] = pt[g*SCB + t];
  __syncthreads();
  if (t == 0){
    int run = 0;
    for (int b=0;b<SCB;b++){ int c = sh[b]; sh[b] = run; run += c; }
  }
  __syncthreads();
  if (t < SCB) pt[g*SCB + t] = sh[t];
}

__global__ __launch_bounds__(1024) void k_scan_apply(float* fb, int* ib, const int* pt,
                                                     const int* parts_no) {
  int g = blockIdx.y;
  float* fg = fb + (size_t)g*GF;
  int* ig = ib + (size_t)g*GI;
  int i = blockIdx.x*1024 + threadIdx.x;
  if (i >= N) return;
  int base = pt[g*SCB + blockIdx.x];
  int r = ig[RP_OFF + i] + base;
  ig[RP_OFF + i] = r;
  int c = ig[CT_OFF + i];
  int o = 0;
  #pragma unroll
  for (int s=0;s<BPR;s++) o += parts_no[((size_t)g*BPR+s)*N + i];
  fg[NI_OFF + i] = rsqrtf((float)(c+1));                 // +1 self loop
  fg[NO_OFF + i] = rsqrtf((float)(o+1));
  if (i == N-1) ig[RP_OFF + N] = r + c;
}

// per-(slice,bin) exclusive prefix over slices -> exact scatter offsets
__global__ __launch_bounds__(256) void k_slice_off(const int* ib, const int* parts_ct, int* off) {
  int g = blockIdx.y;
  int i = blockIdx.x*256 + threadIdx.x;
  if (i >= N) return;
  int base = ib[(size_t)g*GI + RP_OFF + i];
  #pragma unroll
  for (int s=0;s<BPR;s++){
    size_t idx = ((size_t)g*BPR+s)*N + i;
    off[idx] = base;
    base += parts_ct[idx];
  }
}

// scatter: LDS cursors per range, plain scattered store (no global atomics)
__global__ __launch_bounds__(1024) void k_scatter_r(int* ib, const int* off,
    const int* s0,const int* d0,const int* s1,const int* d1,const int* s2,const int* d2) {
  int sl = blockIdx.x, r = blockIdx.y, g = blockIdx.z;
  const int* s = g==0?s0:(g==1?s1:s2);
  const int* d = g==0?d0:(g==1?d1:d2);
  int* ss = ib + (size_t)g*GI + SS_OFF;
  __shared__ int cur[BINS];
  int lo = r*BINS;
  size_t ob = ((size_t)g*BPR + sl)*N + lo;
  for (int i=threadIdx.x;i<BINS;i+=1024) cur[i] = off[ob+i];
  __syncthreads();
  int e0 = sl*ES, e1 = e0+ES;
  for (int e=e0+threadIdx.x; e<e1; e+=1024){
    int ds = d[e];
    if (ds>=lo && ds<lo+BINS){
      int pos = atomicAdd(&cur[ds-lo],1);
      ss[pos] = s[e];
    }
  }
}

__global__ __launch_bounds__(256) void k_copyx(float* fb, const float* x0,const float* x1,const float* x2) {
  int i = blockIdx.x*256 + threadIdx.x;
  int g = blockIdx.y;
  const float* x = g==0?x0:(g==1?x1:x2);
  if (i < N*H/4) {
    ((float4*)(fb + (size_t)g*GF + X_OFF))[i] = ((const float4*)x)[i];
  }
}

// h = bf16( (x @ W) * no[row] )  -> hb (gather operand, halved bytes)
__global__ __launch_bounds__(256) void k_mm_gcn(float* fb, ushort_t* hb,
    const float* W0,const float* W1,const float* W2) {
  int g = blockIdx.y;
  const float* W = g==0?W0:(g==1?W1:W2);
  __shared__ float Ws[64*64];
  for (int i=threadIdx.x; i<4096; i+=256) Ws[i] = W[i];
  __syncthreads();
  int row = blockIdx.x*256 + threadIdx.x;
  if (row >= N) return;
  float* fg = fb + (size_t)g*GF;
  const float4* x4 = (const float4*)(fg + X_OFF + (size_t)row*H);
  float4 xr[16];
  #pragma unroll
  for (int k=0;k<16;k++) xr[k] = x4[k];
  float acc[64];
  #pragma unroll
  for (int j=0;j<64;j++) acc[j] = 0.f;
  const float* xs = (const float*)xr;
  #pragma unroll
  for (int k=0;k<64;k++){
    float xk = xs[k];
    #pragma unroll
    for (int j=0;j<64;j++) acc[j] = fmaf(xk, Ws[k*64+j], acc[j]);
  }
  float sc = fg[NO_OFF + row];
  uint_t pk[32];
  #pragma unroll
  for (int j=0;j<32;j++) pk[j] = bfpack2(acc[2*j]*sc, acc[2*j+1]*sc);
  uint4* h4 = (uint4*)(hb + (size_t)g*GH + (size_t)row*64);
  #pragma unroll
  for (int j=0;j<8;j++) h4[j] = ((const uint4*)pk)[j];
}

// h = bf16(x @ Wgat[g]), el/er from fp32 acc
__global__ __launch_bounds__(256) void k_mm_gat(float* fb, ushort_t* hb,
    const float* Wgat, const float* al, const float* ar) {
  int g = blockIdx.y;
  const float* W = Wgat + (size_t)g*4096;
  __shared__ float Ws[64*64];
  __shared__ float als[64], ars[64];
  for (int i=threadIdx.x; i<4096; i+=256) Ws[i] = W[i];
  if (threadIdx.x < 64){ als[threadIdx.x] = al[g*64+threadIdx.x]; ars[threadIdx.x] = ar[g*64+threadIdx.x]; }
  __syncthreads();
  int row = blockIdx.x*256 + threadIdx.x;
  if (row >= N) return;
  float* fg = fb + (size_t)g*GF;
  const float4* x4 = (const float4*)(fg + X_OFF + (size_t)row*H);
  float4 xr[16];
  #pragma unroll
  for (int k=0;k<16;k++) xr[k] = x4[k];
  float acc[64];
  #pragma unroll
  for (int j=0;j<64;j++) acc[j] = 0.f;
  const float* xs = (const float*)xr;
  #pragma unroll
  for (int k=0;k<64;k++){
    float xk = xs[k];
    #pragma unroll
    for (int j=0;j<64;j++) acc[j] = fmaf(xk, Ws[k*64+j], acc[j]);
  }
  uint_t pk[32];
  #pragma unroll
  for (int j=0;j<32;j++) pk[j] = bfpack2(acc[2*j], acc[2*j+1]);
  uint4* h4 = (uint4*)(hb + (size_t)g*GH + (size_t)row*64);
  #pragma unroll
  for (int j=0;j<8;j++) h4[j] = ((const uint4*)pk)[j];
  float el = 0.f, er = 0.f;
  #pragma unroll
  for (int j=0;j<64;j++){ el = fmaf(acc[j], als[j], el); er = fmaf(acc[j], ars[j], er); }
  fg[EL_OFF + row] = el;
  fg[ER_OFF + row] = er;
}

// GCN aggregate + bias + relu -> new x ; fused mean/max readout.
// Per-graph dispatch; 4 nodes per wave (node = w + 12500*i).
__global__ __launch_bounds__(256) void k_gcn_agg(float* fb, const ushort_t* hb, const int* ib,
    const float* b, float* sm, int g) {
  float* fg = fb + (size_t)g*GF;
  const ushort_t* h = hb + (size_t)g*GH;
  const int* ig = ib + (size_t)g*GI;
  int wave = threadIdx.x >> 6, lane = threadIdx.x & 63;
  int w = blockIdx.x*4 + wave;
  const int* rp = ig + RP_OFF;
  const int* ss = ig + SS_OFF;
  float bl = b[lane];
  float vs = 0.f, vm = 0.f;
  #pragma unroll
  for (int i=0;i<4;i++){
    int node = w + NWAVE*i;
    if (node >= N) break;
    float acc = bf2f(h[(size_t)node*64 + lane]);   // self loop (pre-scaled)
    int s0 = rp[node], s1 = rp[node+1];
    int k = s0;
    for (; k + 8 <= s1; k += 8){
      int i0=ss[k],i1=ss[k+1],i2=ss[k+2],i3=ss[k+3];
      int i4=ss[k+4],i5=ss[k+5],i6=ss[k+6],i7=ss[k+7];
      float v0=bf2f(h[(size_t)i0*64+lane]), v1=bf2f(h[(size_t)i1*64+lane]);
      float v2=bf2f(h[(size_t)i2*64+lane]), v3=bf2f(h[(size_t)i3*64+lane]);
      float v4=bf2f(h[(size_t)i4*64+lane]), v5=bf2f(h[(size_t)i5*64+lane]);
      float v6=bf2f(h[(size_t)i6*64+lane]), v7=bf2f(h[(size_t)i7*64+lane]);
      acc += ((v0+v1)+(v2+v3)) + ((v4+v5)+(v6+v7));
    }
    for (; k < s1; k++) acc += bf2f(h[(size_t)ss[k]*64 + lane]);
    float v = acc * fg[NI_OFF+node] + bl;
    v = v > 0.f ? v : 0.f;
    fg[X_OFF + (size_t)node*64 + lane] = v;
    vs += v;
    vm = fmaxf(vm, v);
  }
  __shared__ float ssum[256];
  __shared__ float smax[256];
  ssum[threadIdx.x] = vs;
  smax[threadIdx.x] = vm;
  __syncthreads();
  if (threadIdx.x < 64){
    float s = ssum[lane] + ssum[64+lane] + ssum[128+lane] + ssum[192+lane];
    float mx = fmaxf(fmaxf(smax[lane], smax[64+lane]), fmaxf(smax[128+lane], smax[192+lane]));
    atomicAdd(&sm[g*64 + lane], s);
    atomicMax((int*)sm + 192 + g*64 + lane, __float_as_int(mx));  // v>=0: int order == float order
  }
}

__global__ void k_zero_ro(float* sm) {
  int i = threadIdx.x;
  if (i < 384) sm[i] = 0.f;
}

// readout finalize + cross-graph feature exchange + supernode h row (bf16), el[N]
__global__ void k_exchange(float* fb, ushort_t* hb, float* sm, const float* Wx, const float* bx,
                           const float* Wgat, const float* al, int it) {
  int gt = blockIdx.x;     // target graph
  int t = threadIdx.x;     // 64 threads
  int src, widx;
  if ((it & 1) == 0){ src = (gt==0)?1:(gt==1)?2:0; widx = (gt==0)?1:(gt==1)?0:2; }
  else              { src = (gt==0)?2:(gt==1)?0:1; widx = (gt==0)?5:(gt==1)?3:4; }
  __shared__ float ro[128];
  __shared__ float f[64];
  __shared__ float red[64];
  ro[t]      = sm[src*64 + t] * (1.0f/(float)N);
  ro[64 + t] = __int_as_float(((int*)sm)[192 + src*64 + t]);
  __syncthreads();
  float a = bx[widx*64 + t];
  for (int k=0;k<128;k++) a = fmaf(ro[k], Wx[(size_t)widx*8192 + k*64 + t], a);
  a = a > 0.f ? a : 0.f;
  f[t] = a;
  __syncthreads();
  float* fg = fb + (size_t)gt*GF;
  float hs = 0.f;
  for (int k=0;k<64;k++) hs = fmaf(f[k], Wgat[(size_t)gt*4096 + k*64 + t], hs);
  uint_t u = __float_as_uint(hs);
  hb[(size_t)gt*GH + (size_t)N*64 + t] = (ushort_t)((u + 0x7fffu + ((u>>16)&1u))>>16);
  red[t] = hs * al[gt*64 + t];
  __syncthreads();
  if (t == 0){
    float e = 0.f;
    for (int k=0;k<64;k++) e += red[k];
    fg[EL_OFF + N] = e;                      // el for supernode
  }
}

// per-dst softmax prep: store exp(e-m) per CSR edge, denominators, self/sup numerators
__global__ __launch_bounds__(256) void k_gat_prep(float* fb, const int* ib) {
  int i = blockIdx.x*256 + threadIdx.x;
  int g = blockIdx.y;
  if (i >= N) return;
  float* fg = fb + (size_t)g*GF;
  const int* ig = ib + (size_t)g*GI;
  const int* rp = ig + RP_OFF;
  const int* ss = ig + SS_OFF;
  const float* el = fg + EL_OFF;
  float eri = fg[ER_OFF + i];
  float* ee = fg + EE_OFF;
  float elsup = el[N];
  int s0 = rp[i], s1 = rp[i+1];
  auto lk = [](float x){ return x >= 0.f ? x : 0.2f*x; };
  float eself = lk(el[i] + eri);
  float esup  = lk(elsup + eri);
  float m = fmaxf(eself, esup);
  int k = s0;
  for (; k + 4 <= s1; k += 4){
    int i0=ss[k],i1=ss[k+1],i2=ss[k+2],i3=ss[k+3];
    float e0=lk(el[i0]+eri), e1=lk(el[i1]+eri);
    float e2=lk(el[i2]+eri), e3=lk(el[i3]+eri);
    ee[k]=e0; ee[k+1]=e1; ee[k+2]=e2; ee[k+3]=e3;
    m = fmaxf(m, fmaxf(fmaxf(e0,e1), fmaxf(e2,e3)));
  }
  for (; k < s1; k++){
    float e = lk(el[ss[k]] + eri);
    ee[k] = e;
    m = fmaxf(m, e);
  }
  float s = 0.f;
  k = s0;
  for (; k + 4 <= s1; k += 4){
    float t0 = __expf(ee[k]-m),   t1 = __expf(ee[k+1]-m);
    float t2 = __expf(ee[k+2]-m), t3 = __expf(ee[k+3]-m);
    ee[k]=t0; ee[k+1]=t1; ee[k+2]=t2; ee[k+3]=t3;
    s += (t0+t1)+(t2+t3);
  }
  for (; k < s1; k++){
    float t = __expf(ee[k] - m);
    ee[k] = t;
    s += t;
  }
  float tself = __expf(eself - m), tsup = __expf(esup - m);
  s += tself + tsup;
  fg[IS_OFF + i]   = 1.0f / s;
  fg[ASLF_OFF + i] = tself;
  fg[ASUP_OFF + i] = tsup;
}

// GAT weighted aggregation -> new x ; per-graph dispatch, 4 nodes per wave.
__global__ __launch_bounds__(256) void k_gat_agg(float* fb, const ushort_t* hb, const int* ib,
    const float* bgat, int g) {
  float* fg = fb + (size_t)g*GF;
  const ushort_t* h = hb + (size_t)g*GH;
  const int* ig = ib + (size_t)g*GI;
  int wave = threadIdx.x >> 6, lane = threadIdx.x & 63;
  int w = blockIdx.x*4 + wave;
  const int* rp = ig + RP_OFF;
  const int* ss = ig + SS_OFF;
  const float* ee = fg + EE_OFF;
  float sup = bf2f(h[(size_t)N*64 + lane]);
  float bl = bgat[g*64 + lane];
  #pragma unroll
  for (int i=0;i<4;i++){
    int node = w + NWAVE*i;
    if (node >= N) break;
    float acc = fg[ASLF_OFF+node] * bf2f(h[(size_t)node*64 + lane])
              + fg[ASUP_OFF+node] * sup;
    int s0 = rp[node], s1 = rp[node+1];
    int k = s0;
    for (; k + 8 <= s1; k += 8){
      int i0=ss[k],i1=ss[k+1],i2=ss[k+2],i3=ss[k+3];
      int i4=ss[k+4],i5=ss[k+5],i6=ss[k+6],i7=ss[k+7];
      float w0=ee[k],w1=ee[k+1],w2=ee[k+2],w3=ee[k+3];
      float w4=ee[k+4],w5=ee[k+5],w6=ee[k+6],w7=ee[k+7];
      float a0 = fmaf(w0, bf2f(h[(size_t)i0*64+lane]), w1 * bf2f(h[(size_t)i1*64+lane]));
      float a1 = fmaf(w2, bf2f(h[(size_t)i2*64+lane]), w3 * bf2f(h[(size_t)i3*64+lane]));
      float a2 = fmaf(w4, bf2f(h[(size_t)i4*64+lane]), w5 * bf2f(h[(size_t)i5*64+lane]));
      float a3 = fmaf(w6, bf2f(h[(size_t)i6*64+lane]), w7 * bf2f(h[(size_t)i7*64+lane]));
      acc += (a0+a1)+(a2+a3);
    }
    for (; k < s1; k++) acc = fmaf(ee[k], bf2f(h[(size_t)ss[k]*64 + lane]), acc);
    fg[X_OFF + (size_t)node*64 + lane] = acc * fg[IS_OFF+node] + bl;
  }
}

__global__ __launch_bounds__(384) void k_mlp(const float* sm, const float* W1, const float* b1,
    const float* W2, const float* b2, const float* W3, const float* b3, float* out) {
  __shared__ float nf[384];
  __shared__ float y1[192];
  __shared__ float y2[96];
  __shared__ float z[2];
  int t = threadIdx.x;
  int g = t / 128, j = t % 128;
  nf[t] = (j < 64) ? sm[g*64 + j] * (1.0f/(float)N)
                   : __int_as_float(((const int*)sm)[192 + g*64 + (j-64)]);
  __syncthreads();
  if (t < 192){
    float a = b1[t];
    for (int k=0;k<384;k++) a = fmaf(nf[k], W1[(size_t)k*192 + t], a);
    y1[t] = a > 0.f ? a : 0.f;
  }
  __syncthreads();
  if (t < 96){
    float a = b2[t];
    for (int k=0;k<192;k++) a = fmaf(y1[k], W2[(size_t)k*96 + t], a);
    y2[t] = a > 0.f ? a : 0.f;
  }
  __syncthreads();
  if (t < 2){
    float a = b3[t];
    for (int k=0;k<96;k++) a = fmaf(y2[k], W3[k*2 + t], a);
    z[t] = a;
  }
  __syncthreads();
  if (t == 0){
    float m = fmaxf(z[0], z[1]);
    float l = m + logf(__expf(z[0]-m) + __expf(z[1]-m));
    out[0] = z[0] - l;
    out[1] = z[1] - l;
  }
}

extern "C" void kernel_launch(void* const* d_in, const int* in_sizes, int n_in,
                              void* d_out, int out_size, void* d_ws, size_t ws_size,
                              hipStream_t stream) {
  const float* x_s  = (const float*)d_in[0];
  const float* x_g  = (const float*)d_in[1];
  const float* x_t  = (const float*)d_in[2];
  const float* Wc_s = (const float*)d_in[3];
  const float* bc_s = (const float*)d_in[4];
  const float* Wc_g = (const float*)d_in[5];
  const float* bc_g = (const float*)d_in[6];
  const float* Wc_t = (const float*)d_in[7];
  const float* bc_t = (const float*)d_in[8];
  const float* Wx   = (const float*)d_in[9];
  const float* bx   = (const float*)d_in[10];
  const float* Wgat = (const float*)d_in[11];
  const float* al   = (const float*)d_in[12];
  const float* ar   = (const float*)d_in[13];
  const float* bgat = (const float*)d_in[14];
  const float* W1   = (const float*)d_in[15];
  const float* b1   = (const float*)d_in[16];
  const float* W2   = (const float*)d_in[17];
  const float* b2   = (const float*)d_in[18];
  const float* W3   = (const float*)d_in[19];
  const float* b3   = (const float*)d_in[20];
  const int* src_s  = (const int*)d_in[21];
  const int* dst_s  = (const int*)d_in[22];
  const int* src_g  = (const int*)d_in[23];
  const int* dst_g  = (const int*)d_in[24];
  const int* src_t  = (const int*)d_in[25];
  const int* dst_t  = (const int*)d_in[26];

  float* fb = (float*)d_ws;
  int*   ib = (int*)(fb + 3*GF);
  ushort_t* hb = (ushort_t*)(ib + 3*GI);
  float* sm = (float*)(hb + 3*GH);
  int*   pt = (int*)(sm + 384);              // 3*SCB scan partials
  int*   parts_ct = pt + 3*SCB + 64;         // 3*BPR*N
  int*   parts_no = parts_ct + (size_t)3*BPR*N;
  int*   off      = parts_no + (size_t)3*BPR*N;
  float* out = (float*)d_out;

  dim3 b256(256);
  const float* bcs[3][3] = {{bc_s, bc_g, bc_t},{bc_s+64, bc_g+64, bc_t+64},{bc_s+128, bc_g+128, bc_t+128}};

  // graph prep: LDS-histogram counting sort (no global atomics)
  k_hist      <<<dim3(BPR, RNG, 3),  dim3(1024), 0, stream>>>(parts_ct, parts_no, src_s,dst_s, src_g,dst_g, src_t,dst_t);
  k_scan_local<<<dim3(SCB, 3),       dim3(1024), 0, stream>>>(ib, pt, parts_ct);
  k_scan_part <<<dim3(3),              dim3(64), 0, stream>>>(pt);
  k_scan_apply<<<dim3(SCB, 3),       dim3(1024), 0, stream>>>(fb, ib, pt, parts_no);
  k_slice_off <<<dim3((N+255)/256, 3),     b256, 0, stream>>>(ib, parts_ct, off);
  k_scatter_r <<<dim3(BPR, RNG, 3),  dim3(1024), 0, stream>>>(ib, off, src_s,dst_s, src_g,dst_g, src_t,dst_t);
  k_copyx     <<<dim3((N*H/4+255)/256, 3), b256, 0, stream>>>(fb, x_s, x_g, x_t);

  for (int it = 0; it < 2; ++it) {
    k_zero_ro <<<1, 384, 0, stream>>>(sm);
    k_mm_gcn  <<<dim3((N+255)/256, 3), b256, 0, stream>>>(fb, hb, Wc_s + it*4096, Wc_g + it*4096, Wc_t + it*4096);
    for (int g = 0; g < 3; ++g)
      k_gcn_agg <<<dim3(NWAVE/4), b256, 0, stream>>>(fb, hb, ib, bcs[it][g], sm, g);
    k_exchange<<<dim3(3), dim3(64), 0, stream>>>(fb, hb, sm, Wx, bx, Wgat, al, it);
    k_mm_gat  <<<dim3((N+255)/256, 3), b256, 0, stream>>>(fb, hb, Wgat, al, ar);
    k_gat_prep<<<dim3((N+255)/256, 3), b256, 0, stream>>>(fb, ib);
    for (int g = 0; g < 3; ++g)
      k_gat_agg <<<dim3(NWAVE/4), b256, 0, stream>>>(fb, hb, ib, bgat, g);
  }

  // final layer readouts + MLP head
  k_zero_ro <<<1, 384, 0, stream>>>(sm);
  k_mm_gcn  <<<dim3((N+255)/256, 3), b256, 0, stream>>>(fb, hb, Wc_s + 2*4096, Wc_g + 2*4096, Wc_t + 2*4096);
  for (int g = 0; g < 3; ++g)
    k_gcn_agg <<<dim3(NWAVE/4), b256, 0, stream>>>(fb, hb, ib, bcs[2][g], sm, g);
  k_mlp     <<<1, 384, 0, stream>>>(sm, W1, b1, W2, b2, W3, b3, out);
}